// Round 1
// baseline (2319.251 us; speedup 1.0000x reference)
//
#include <hip/hip_runtime.h>
#include <math.h>

#define B_    8
#define C_    64
#define N_    4096
#define OUT_  64
#define KNN_  20
#define KP_   24   // phase-1 candidate count (4 slack over K for f32->f64 re-rank)

// ---------------------------------------------------------------------------
// Kernel 1: per-point projections u = (W1-W2)·p, v = W2·p, and squared norms
// x: [B, C, N] (f32). u,v: [B*N, 64]. sq32/sq64: [B*N].
// ---------------------------------------------------------------------------
__global__ __launch_bounds__(256) void k_uv(const float* __restrict__ x,
                                            const float* __restrict__ W,
                                            float* __restrict__ u,
                                            float* __restrict__ v,
                                            float* __restrict__ sq32,
                                            double* __restrict__ sq64) {
    __shared__ float Wd[64 * 64];   // [c][o] = W1 - W2
    __shared__ float W2s[64 * 64];  // [c][o] = W2
    const int tid = threadIdx.x;
    for (int k = 0; k < 16; ++k) {
        int i = tid + k * 256;
        int o = i & 63, c = i >> 6;
        float w1 = W[o * 128 + c];
        float w2 = W[o * 128 + 64 + c];
        Wd[c * 64 + o]  = w1 - w2;
        W2s[c * 64 + o] = w2;
    }
    __syncthreads();
    const int o = tid & 63, w = tid >> 6;
    const int row = blockIdx.x * 4 + w;         // < 32768
    const int b = row >> 12, n = row & (N_ - 1);
    const float* xp = x + (size_t)b * C_ * N_ + n;
    float ua = 0.f, va = 0.f;
    double sq = 0.0;
    for (int c = 0; c < 64; ++c) {
        float xc = xp[(size_t)c * N_];          // broadcast across the wave
        ua = fmaf(Wd[c * 64 + o], xc, ua);
        va = fmaf(W2s[c * 64 + o], xc, va);
        double xd = (double)xc;
        sq = fma(xd, xd, sq);
    }
    u[(size_t)row * 64 + o] = ua;
    v[(size_t)row * 64 + o] = va;
    if (o == 0) { sq64[row] = sq; sq32[row] = (float)sq; }
}

// ---------------------------------------------------------------------------
// Kernel 2: fused f32 Gram + per-row top-24 (smallest score = sq_j - 2*dot).
// 64 rows/block, 128-col tiles, 128 threads: thread = (rg 0..7, cg 0..15),
// register tile 8 rows x 8 cols. Unsorted 24-list per row in LDS, threshold
// maintained by 16-lane shuffle max-reduce; ballot-serialized insertions.
// ---------------------------------------------------------------------------
__global__ __launch_bounds__(128) void k_knn(const float* __restrict__ x,
                                             const float* __restrict__ sq32,
                                             int* __restrict__ idx24) {
    __shared__ float4 colv[64 * 32];    // [c][32 f4 slots], xor-swizzled
    __shared__ float  rowv[64 * 68];    // [r][c], stride 68 (16B-aligned rows)
    __shared__ float  lsc[64 * KP_];
    __shared__ int    lix[64 * KP_];
    __shared__ int    lcnt[64];
    __shared__ float  lthr[64];
    __shared__ int    lmax[64];

    const int tid = threadIdx.x;
    const int b = blockIdx.x >> 6;                 // blockIdx / (N/64)
    const int rowBase = (blockIdx.x & 63) << 6;
    const float* __restrict__ xb = x + (size_t)b * C_ * N_;

    // stage the block's 64 row-points
    for (int k = 0; k < 32; ++k) {
        int i = tid + k * 128;
        int c = i >> 6, r = i & 63;
        rowv[r * 68 + c] = xb[(size_t)c * N_ + rowBase + r];
    }
    if (tid < 64) lcnt[tid] = 0;

    const int rg  = tid >> 4;          // 0..7
    const int cg  = tid & 15;          // 0..15
    const int rgw = (tid & 63) >> 4;   // row-group within wave (0..3)
    const int sw0 = (cg * 2)     ^ (((cg * 2)     >> 3) & 3);
    const int sw1 = (cg * 2 + 1) ^ (((cg * 2 + 1) >> 3) & 3);

    volatile float* vsc  = lsc;
    volatile int*   vix  = lix;
    volatile int*   vcnt = lcnt;
    volatile float* vthr = lthr;
    volatile int*   vmax = lmax;

    for (int jt = 0; jt < N_; jt += 128) {
        __syncthreads();
        // stage column tile, xor-swizzled in 16B units for conflict-free reads
        for (int k = 0; k < 16; ++k) {
            int i4 = tid + k * 128;
            int c = i4 >> 5, jf = i4 & 31;
            float4 val = *(const float4*)(xb + (size_t)c * N_ + jt + jf * 4);
            colv[c * 32 + (jf ^ ((jf >> 3) & 3))] = val;
        }
        __syncthreads();

        float acc[8][8];
        #pragma unroll
        for (int i = 0; i < 8; ++i) {
            #pragma unroll
            for (int j = 0; j < 8; ++j) acc[i][j] = 0.f;
        }

        for (int c4 = 0; c4 < 16; ++c4) {
            float4 rv[8];
            #pragma unroll
            for (int i = 0; i < 8; ++i)
                rv[i] = *(const float4*)&rowv[(rg * 8 + i) * 68 + c4 * 4];
            #pragma unroll
            for (int cc = 0; cc < 4; ++cc) {
                const float4 ca = colv[(c4 * 4 + cc) * 32 + sw0];
                const float4 cb = colv[(c4 * 4 + cc) * 32 + sw1];
                #pragma unroll
                for (int i = 0; i < 8; ++i) {
                    const float r = (cc == 0) ? rv[i].x : (cc == 1) ? rv[i].y
                                   : (cc == 2) ? rv[i].z : rv[i].w;
                    acc[i][0] = fmaf(r, ca.x, acc[i][0]);
                    acc[i][1] = fmaf(r, ca.y, acc[i][1]);
                    acc[i][2] = fmaf(r, ca.z, acc[i][2]);
                    acc[i][3] = fmaf(r, ca.w, acc[i][3]);
                    acc[i][4] = fmaf(r, cb.x, acc[i][4]);
                    acc[i][5] = fmaf(r, cb.y, acc[i][5]);
                    acc[i][6] = fmaf(r, cb.z, acc[i][6]);
                    acc[i][7] = fmaf(r, cb.w, acc[i][7]);
                }
            }
        }

        float sqj[8];
        {
            const float4 q0 = *(const float4*)(sq32 + b * N_ + jt + cg * 8);
            const float4 q1 = *(const float4*)(sq32 + b * N_ + jt + cg * 8 + 4);
            sqj[0] = q0.x; sqj[1] = q0.y; sqj[2] = q0.z; sqj[3] = q0.w;
            sqj[4] = q1.x; sqj[5] = q1.y; sqj[6] = q1.z; sqj[7] = q1.w;
        }

        #pragma unroll 1
        for (int i = 0; i < 8; ++i) {
            const int row = rg * 8 + i;
            float s[8];
            #pragma unroll
            for (int cc = 0; cc < 8; ++cc) s[cc] = fmaf(-2.f, acc[i][cc], sqj[cc]);

            int cnt0 = vcnt[row];
            float thr = (cnt0 < KP_) ? INFINITY : vthr[row];
            unsigned m = 0u;
            #pragma unroll
            for (int cc = 0; cc < 8; ++cc) if (s[cc] < thr) m |= (1u << cc);

            while (true) {
                unsigned long long bal = __ballot(m != 0u);
                unsigned grp = (unsigned)((bal >> (rgw * 16)) & 0xFFFFull);
                if (!grp) break;
                int leader = __ffs((int)grp) - 1;
                if (cg == leader) {
                    int cc = __ffs((int)m) - 1;
                    m &= (m - 1u);
                    float sv = s[0];
                    #pragma unroll
                    for (int t = 1; t < 8; ++t) if (cc == t) sv = s[t];  // static idx
                    int jv = jt + cg * 8 + cc;
                    int c2 = vcnt[row];
                    if (c2 < KP_) {
                        vsc[row * KP_ + c2] = sv;
                        vix[row * KP_ + c2] = jv;
                        vcnt[row] = c2 + 1;
                    } else {
                        int mp = vmax[row];
                        vsc[row * KP_ + mp] = sv;
                        vix[row * KP_ + mp] = jv;
                    }
                }
                int c3 = vcnt[row];
                if (c3 == KP_) {
                    // group max-reduce over the 24 entries -> new threshold
                    float bv = vsc[row * KP_ + cg];
                    int bp = cg;
                    if (cg + 16 < KP_) {
                        float ov = vsc[row * KP_ + cg + 16];
                        if (ov > bv) { bv = ov; bp = cg + 16; }
                    }
                    #pragma unroll
                    for (int d = 1; d < 16; d <<= 1) {
                        float ov = __shfl_xor(bv, d);
                        int   op = __shfl_xor(bp, d);
                        if (ov > bv || (ov == bv && op < bp)) { bv = ov; bp = op; }
                    }
                    if (cg == 0) { vthr[row] = bv; vmax[row] = bp; }
                    float thr2 = bv;
                    #pragma unroll
                    for (int cc = 0; cc < 8; ++cc)
                        if (((m >> cc) & 1u) && !(s[cc] < thr2)) m &= ~(1u << cc);
                }
            }
        }
    }
    __syncthreads();
    for (int k = 0; k < 12; ++k) {      // 64*24 / 128
        int i = tid + k * 128;
        int r = i / KP_, c2 = i % KP_;
        idx24[((size_t)(b * N_ + rowBase + r)) * KP_ + c2] = lix[r * KP_ + c2];
    }
}

// ---------------------------------------------------------------------------
// Kernel 3: f64 re-rank of the 24 candidates with the exact reference formula
// d2 = (sq_n + sq_j) - 2*dot  -> write the 20 smallest (ties: smaller index).
// ---------------------------------------------------------------------------
__global__ __launch_bounds__(256) void k_rerank(const float* __restrict__ x,
                                                const double* __restrict__ sq64,
                                                const int* __restrict__ idx24,
                                                int* __restrict__ idx20) {
    __shared__ double dd[8 * KP_];
    __shared__ int    ii[8 * KP_];
    const int tid = threadIdx.x;
    const int rl = tid >> 5;       // row-in-block 0..7
    const int lane = tid & 31;
    const int row = blockIdx.x * 8 + rl;
    const int b = row >> 12, n = row & (N_ - 1);
    const int cand = (lane < KP_) ? idx24[(size_t)row * KP_ + lane] : 0;
    const float* __restrict__ xb = x + (size_t)b * C_ * N_;
    double dot = 0.0;
    #pragma unroll 4
    for (int c = 0; c < C_; ++c) {
        double xn = (double)xb[(size_t)c * N_ + n];
        double xj = (double)xb[(size_t)c * N_ + cand];
        dot = fma(xn, xj, dot);
    }
    double d2 = (sq64[row] + sq64[b * N_ + cand]) - 2.0 * dot;
    if (lane < KP_) { dd[rl * KP_ + lane] = d2; ii[rl * KP_ + lane] = cand; }
    __syncthreads();
    if (lane < KP_) {
        int rank = 0;
        for (int t = 0; t < KP_; ++t) {
            double od = dd[rl * KP_ + t];
            int oi = ii[rl * KP_ + t];
            if (od < d2 || (od == d2 && oi < cand)) ++rank;
        }
        if (rank < KNN_) idx20[(size_t)row * KNN_ + rank] = cand;
    }
}

// ---------------------------------------------------------------------------
// Kernel 4: BN batch stats (sum, sumsq per channel) via recompute of
// y = u_n + v_j + bias.  Deterministic per-block partials.
// ---------------------------------------------------------------------------
__global__ __launch_bounds__(256) void k_stats(const float* __restrict__ u,
                                               const float* __restrict__ v,
                                               const float* __restrict__ bias,
                                               const int* __restrict__ idx20,
                                               float* __restrict__ psum,
                                               float* __restrict__ psq) {
    __shared__ float red[512];
    const int tid = threadIdx.x;
    const int o = tid & 63, w = tid >> 6;
    const int base = blockIdx.x * 128;          // 128 rows per block, same batch
    const int b = base >> 12;
    const float bo = bias[o];
    float s = 0.f, s2 = 0.f;
    for (int nn = w; nn < 128; nn += 4) {
        const int row = base + nn;
        const float uo = u[(size_t)row * 64 + o] + bo;
        const int* ip = idx20 + (size_t)row * KNN_;
        #pragma unroll 4
        for (int k = 0; k < KNN_; ++k) {
            int j = ip[k];
            float y = uo + v[((size_t)b * N_ + j) * 64 + o];
            s += y;
            s2 = fmaf(y, y, s2);
        }
    }
    red[tid] = s;
    red[256 + tid] = s2;
    __syncthreads();
    if (tid < 64) {
        float t  = red[o] + red[64 + o] + red[128 + o] + red[192 + o];
        float t2 = red[256 + o] + red[320 + o] + red[384 + o] + red[448 + o];
        psum[blockIdx.x * 64 + o] = t;
        psq[blockIdx.x * 64 + o]  = t2;
    }
}

// Kernel 4b: finalize BN -> per-channel scale/shift (single tiny block)
__global__ void k_bn(const float* __restrict__ psum, const float* __restrict__ psq,
                     const float* __restrict__ gamma, const float* __restrict__ beta,
                     float* __restrict__ scsh) {
    const int o = threadIdx.x;
    if (o >= 64) return;
    float s = 0.f, s2 = 0.f;
    for (int i = 0; i < 256; ++i) { s += psum[i * 64 + o]; s2 += psq[i * 64 + o]; }
    const float cnt = (float)B_ * (float)N_ * (float)KNN_;
    float mean = s / cnt;
    float var = s2 / cnt - mean * mean;
    float scale = gamma[o] / sqrtf(var + 1e-5f);
    float shift = beta[o] - mean * scale;
    scsh[o] = scale;
    scsh[64 + o] = shift;
}

// ---------------------------------------------------------------------------
// Kernel 5: out[b,o,n] = lrelu(scale*extreme_k(y) + shift); max if scale>=0
// else min (lrelu monotone + affine BN commute with max over k).
// LDS transpose for coalesced [B,OUT,N] stores.
// ---------------------------------------------------------------------------
__global__ __launch_bounds__(256) void k_final(const float* __restrict__ u,
                                               const float* __restrict__ v,
                                               const float* __restrict__ bias,
                                               const int* __restrict__ idx20,
                                               const float* __restrict__ scsh,
                                               float* __restrict__ out) {
    __shared__ float tr[64 * 129];
    const int tid = threadIdx.x;
    const int o = tid & 63, w = tid >> 6;
    const int base = blockIdx.x * 128;
    const int b = base >> 12;
    const int nbase = base & (N_ - 1);
    const float bo = bias[o];
    const float sc = scsh[o];
    const float sh = scsh[64 + o];
    for (int nn = w; nn < 128; nn += 4) {
        const int row = base + nn;
        const float uo = u[(size_t)row * 64 + o] + bo;
        const int* ip = idx20 + (size_t)row * KNN_;
        float mx = -INFINITY, mn = INFINITY;
        #pragma unroll 4
        for (int k = 0; k < KNN_; ++k) {
            int j = ip[k];
            float y = uo + v[((size_t)b * N_ + j) * 64 + o];
            mx = fmaxf(mx, y);
            mn = fminf(mn, y);
        }
        float best = (sc >= 0.f) ? mx : mn;
        float z = fmaf(best, sc, sh);
        tr[o * 129 + nn] = (z >= 0.f) ? z : 0.2f * z;
    }
    __syncthreads();
    for (int k = 0; k < 32; ++k) {      // 64*128 / 256
        int i = tid + k * 256;
        int o2 = i >> 7, n2 = i & 127;
        out[((size_t)b * 64 + o2) * N_ + nbase + n2] = tr[o2 * 129 + n2];
    }
}

// ---------------------------------------------------------------------------
extern "C" void kernel_launch(void* const* d_in, const int* in_sizes, int n_in,
                              void* d_out, int out_size, void* d_ws, size_t ws_size,
                              hipStream_t stream) {
    const float* x     = (const float*)d_in[0];
    const float* W     = (const float*)d_in[1];
    const float* bias  = (const float*)d_in[2];
    const float* gamma = (const float*)d_in[3];
    const float* beta  = (const float*)d_in[4];
    float* out = (float*)d_out;

    char* ws = (char*)d_ws;
    float*  u     = (float*)(ws + 0);           //  8,388,608 B
    float*  v     = (float*)(ws + 8388608);     //  8,388,608 B
    float*  sq32  = (float*)(ws + 16777216);    //    131,072 B
    double* sq64  = (double*)(ws + 16908288);   //    262,144 B
    int*    idx24 = (int*)(ws + 17170432);      //  3,145,728 B
    int*    idx20 = (int*)(ws + 20316160);      //  2,621,440 B
    float*  psum  = (float*)(ws + 22937600);    //     65,536 B
    float*  psq   = (float*)(ws + 23003136);    //     65,536 B
    float*  scsh  = (float*)(ws + 23068672);    //        512 B

    hipLaunchKernelGGL(k_uv,     dim3(8192), dim3(256), 0, stream, x, W, u, v, sq32, sq64);
    hipLaunchKernelGGL(k_knn,    dim3(512),  dim3(128), 0, stream, x, sq32, idx24);
    hipLaunchKernelGGL(k_rerank, dim3(4096), dim3(256), 0, stream, x, sq64, idx24, idx20);
    hipLaunchKernelGGL(k_stats,  dim3(256),  dim3(256), 0, stream, u, v, bias, idx20, psum, psq);
    hipLaunchKernelGGL(k_bn,     dim3(1),    dim3(64),  0, stream, psum, psq, gamma, beta, scsh);
    hipLaunchKernelGGL(k_final,  dim3(256),  dim3(256), 0, stream, u, v, bias, idx20, scsh, out);
}

// Round 2
// 1835.482 us; speedup vs baseline: 1.2636x; 1.2636x over previous
//
#include <hip/hip_runtime.h>
#include <math.h>

#define B_    8
#define C_    64
#define N_    4096
#define OUT_  64
#define KNN_  20
#define KP_   24   // phase-1 candidate count (4 slack over K for f32->f64 re-rank)
#define CAP_  40   // per-row LDS candidate list capacity
#define KEEP_ 24   // compaction keep count (== KP_)

// ---------------------------------------------------------------------------
// Kernel 1: per-point projections u = (W1-W2)·p, v = W2·p, and squared norms
// ---------------------------------------------------------------------------
__global__ __launch_bounds__(256) void k_uv(const float* __restrict__ x,
                                            const float* __restrict__ W,
                                            float* __restrict__ u,
                                            float* __restrict__ v,
                                            float* __restrict__ sq32,
                                            double* __restrict__ sq64) {
    __shared__ float Wd[64 * 64];   // [c][o] = W1 - W2
    __shared__ float W2s[64 * 64];  // [c][o] = W2
    const int tid = threadIdx.x;
    for (int k = 0; k < 16; ++k) {
        int i = tid + k * 256;
        int o = i & 63, c = i >> 6;
        float w1 = W[o * 128 + c];
        float w2 = W[o * 128 + 64 + c];
        Wd[c * 64 + o]  = w1 - w2;
        W2s[c * 64 + o] = w2;
    }
    __syncthreads();
    const int o = tid & 63, w = tid >> 6;
    const int row = blockIdx.x * 4 + w;         // < 32768
    const int b = row >> 12, n = row & (N_ - 1);
    const float* xp = x + (size_t)b * C_ * N_ + n;
    float ua = 0.f, va = 0.f;
    double sq = 0.0;
    for (int c = 0; c < 64; ++c) {
        float xc = xp[(size_t)c * N_];          // broadcast across the wave
        ua = fmaf(Wd[c * 64 + o], xc, ua);
        va = fmaf(W2s[c * 64 + o], xc, va);
        double xd = (double)xc;
        sq = fma(xd, xd, sq);
    }
    u[(size_t)row * 64 + o] = ua;
    v[(size_t)row * 64 + o] = va;
    if (o == 0) { sq64[row] = sq; sq32[row] = (float)sq; }
}

// ---------------------------------------------------------------------------
// Kernel 2: fused f32 Gram + per-row top-24.
// 64 rows/block, 128-col tiles (staged in two 32-channel halves), 128 threads:
// thread = (rg 0..7, cg 0..15), register tile 8 rows x 8 cols.
// Selection: per-row 40-entry LDS list, bulk atomicAdd append gated by a
// threshold = certified upper bound on the running 24th-best (score,idx) key;
// when full, a 16-lane rank-based compaction keeps the exact top-24 and
// tightens the threshold. Final rank pass emits the exact top-24.
// ---------------------------------------------------------------------------
__device__ __forceinline__ void seg_rank_compact(float* lsc, int* lix, int* cnt,
                                                 float* thr_s, int* thr_i,
                                                 int r, int cg) {
    // precondition: list slots 0..CAP_-1 valid (list full)
    float a0 = lsc[r * CAP_ + cg];       int x0 = lix[r * CAP_ + cg];
    float a1 = lsc[r * CAP_ + cg + 16];  int x1 = lix[r * CAP_ + cg + 16];
    const bool h2 = (cg + 32) < CAP_;
    float a2 = h2 ? lsc[r * CAP_ + cg + 32] : 0.f;
    int   x2 = h2 ? lix[r * CAP_ + cg + 32] : 0x7fffffff;
    int r0 = 0, r1 = 0, r2 = 0;
    for (int t = 0; t < CAP_; ++t) {
        float bs = lsc[r * CAP_ + t];
        int   bi = lix[r * CAP_ + t];
        r0 += (bs < a0) || (bs == a0 && bi < x0);
        r1 += (bs < a1) || (bs == a1 && bi < x1);
        r2 += (bs < a2) || (bs == a2 && bi < x2);
    }
    // writes depend on ranks (all reads done); wave-lockstep keeps lanes aligned
    if (r0 < KEEP_) { lsc[r * CAP_ + r0] = a0; lix[r * CAP_ + r0] = x0; }
    if (r1 < KEEP_) { lsc[r * CAP_ + r1] = a1; lix[r * CAP_ + r1] = x1; }
    if (h2 && r2 < KEEP_) { lsc[r * CAP_ + r2] = a2; lix[r * CAP_ + r2] = x2; }
    if (r0 == KEEP_ - 1) { thr_s[r] = a0; thr_i[r] = x0; }
    if (r1 == KEEP_ - 1) { thr_s[r] = a1; thr_i[r] = x1; }
    if (h2 && r2 == KEEP_ - 1) { thr_s[r] = a2; thr_i[r] = x2; }
    if (cg == 0) cnt[r] = KEEP_;
}

__global__ __launch_bounds__(128) void k_knn(const float* __restrict__ x,
                                             const float* __restrict__ sq32,
                                             int* __restrict__ idx24) {
    __shared__ float4 colA[32 * 32];       // [32 ch][32 f4 cols], xor-swizzled: 16 KB
    __shared__ float  rowv[16 * 64 * 4];   // [c4][slot][ch4], slot=(r&7)*8+(r>>3): 16 KB
    __shared__ float  lsc[64 * CAP_];      // 10 KB
    __shared__ int    lix[64 * CAP_];      // 10 KB
    __shared__ int    lcnt[64];
    __shared__ float  lthr_s[64];
    __shared__ int    lthr_i[64];

    const int tid = threadIdx.x;
    const int b = blockIdx.x >> 6;
    const int rowBase = (blockIdx.x & 63) << 6;
    const float* __restrict__ xb = x + (size_t)b * C_ * N_;

    // stage the block's 64 row-points: c4-major, row-slot interleaved so the
    // wave's 4 co-read rows (8 apart) land in adjacent 16B lines (no conflicts)
    for (int k = 0; k < 32; ++k) {
        int i = tid + k * 128;
        int c = i >> 6, r = i & 63;
        rowv[(((c >> 2) * 64) + ((r & 7) * 8 + (r >> 3))) * 4 + (c & 3)] =
            xb[(size_t)c * N_ + rowBase + r];
    }
    if (tid < 64) {
        lcnt[tid] = 0;
        lthr_s[tid] = INFINITY;
        lthr_i[tid] = 0x7fffffff;
    }

    const int rg  = tid >> 4;          // 0..7
    const int cg  = tid & 15;          // 0..15
    const int rgw = (tid & 63) >> 4;   // segment (quarter-wave) id 0..3
    const int segbase = rgw * 16;
    const int sw0 = (cg * 2)     ^ (((cg * 2)     >> 3) & 3);
    const int sw1 = (cg * 2 + 1) ^ (((cg * 2 + 1) >> 3) & 3);

    for (int jt = 0; jt < N_; jt += 128) {
        float acc[8][8];
        #pragma unroll
        for (int i = 0; i < 8; ++i)
            #pragma unroll
            for (int j = 0; j < 8; ++j) acc[i][j] = 0.f;

        // two 32-channel halves share the 16 KB colA buffer
        for (int half = 0; half < 2; ++half) {
            __syncthreads();   // everyone done reading colA (prev half/tile)
            const int chbase = half * 32;
            for (int k = 0; k < 8; ++k) {
                int i4 = tid + k * 128;
                int c = i4 >> 5, jf = i4 & 31;
                float4 val = *(const float4*)(xb + (size_t)(chbase + c) * N_ + jt + jf * 4);
                colA[c * 32 + (jf ^ ((jf >> 3) & 3))] = val;
            }
            __syncthreads();

            for (int c4h = 0; c4h < 8; ++c4h) {
                const int c4g = half * 8 + c4h;
                float4 rv[8];
                #pragma unroll
                for (int i = 0; i < 8; ++i)
                    rv[i] = *(const float4*)&rowv[(c4g * 64 + (i * 8 + rg)) * 4];
                #pragma unroll
                for (int cc = 0; cc < 4; ++cc) {
                    const float4 ca = colA[(c4h * 4 + cc) * 32 + sw0];
                    const float4 cb = colA[(c4h * 4 + cc) * 32 + sw1];
                    #pragma unroll
                    for (int i = 0; i < 8; ++i) {
                        const float r = (cc == 0) ? rv[i].x : (cc == 1) ? rv[i].y
                                       : (cc == 2) ? rv[i].z : rv[i].w;
                        acc[i][0] = fmaf(r, ca.x, acc[i][0]);
                        acc[i][1] = fmaf(r, ca.y, acc[i][1]);
                        acc[i][2] = fmaf(r, ca.z, acc[i][2]);
                        acc[i][3] = fmaf(r, ca.w, acc[i][3]);
                        acc[i][4] = fmaf(r, cb.x, acc[i][4]);
                        acc[i][5] = fmaf(r, cb.y, acc[i][5]);
                        acc[i][6] = fmaf(r, cb.z, acc[i][6]);
                        acc[i][7] = fmaf(r, cb.w, acc[i][7]);
                    }
                }
            }
        }

        float sqj[8];
        {
            const float4 q0 = *(const float4*)(sq32 + b * N_ + jt + cg * 8);
            const float4 q1 = *(const float4*)(sq32 + b * N_ + jt + cg * 8 + 4);
            sqj[0] = q0.x; sqj[1] = q0.y; sqj[2] = q0.z; sqj[3] = q0.w;
            sqj[4] = q1.x; sqj[5] = q1.y; sqj[6] = q1.z; sqj[7] = q1.w;
        }
        const int col0 = jt + cg * 8;

        // ---- selection: bulk append + rare compaction, per row ----
        #pragma unroll
        for (int i = 0; i < 8; ++i) {
            const int r = rg * 8 + i;
            float s[8];
            #pragma unroll
            for (int cc = 0; cc < 8; ++cc) s[cc] = fmaf(-2.f, acc[i][cc], sqj[cc]);

            float ts = lthr_s[r];
            int   ti = lthr_i[r];
            unsigned m = 0u;
            #pragma unroll
            for (int cc = 0; cc < 8; ++cc)
                if (s[cc] < ts || (s[cc] == ts && (col0 + cc) < ti)) m |= (1u << cc);

            while (true) {
                unsigned long long bal = __ballot(m != 0u);
                if (((unsigned)(bal >> segbase) & 0xFFFFu) == 0u) break;
                bool fail = false;
                #pragma unroll
                for (int cc = 0; cc < 8; ++cc) {
                    if (((m >> cc) & 1u) && !fail) {
                        int slot = atomicAdd(&lcnt[r], 1);
                        if (slot < CAP_) {
                            lsc[r * CAP_ + slot] = s[cc];
                            lix[r * CAP_ + slot] = col0 + cc;
                            m &= ~(1u << cc);
                        } else {
                            fail = true;
                        }
                    }
                }
                unsigned long long fb = __ballot(fail);
                if (((unsigned)(fb >> segbase) & 0xFFFFu) != 0u) {
                    seg_rank_compact(lsc, lix, lcnt, lthr_s, lthr_i, r, cg);
                    ts = lthr_s[r];
                    ti = lthr_i[r];
                    #pragma unroll
                    for (int cc = 0; cc < 8; ++cc) {
                        if ((m >> cc) & 1u) {
                            bool p = (s[cc] < ts) || (s[cc] == ts && (col0 + cc) < ti);
                            if (!p) m &= ~(1u << cc);
                        }
                    }
                }
            }
        }
    }

    // ---- final: exact top-24 per row by (score, idx) rank; write idx24 ----
    #pragma unroll 1
    for (int i = 0; i < 8; ++i) {
        const int r = rg * 8 + i;
        int len = lcnt[r];
        len = (len < CAP_) ? len : CAP_;
        float a0 = 0.f, a1 = 0.f, a2 = 0.f;
        int x0 = 0, x1 = 0, x2 = 0;
        const bool h0 = cg < len, h1 = (cg + 16) < len, h2v = (cg + 32) < len;
        if (h0)  { a0 = lsc[r * CAP_ + cg];      x0 = lix[r * CAP_ + cg]; }
        if (h1)  { a1 = lsc[r * CAP_ + cg + 16]; x1 = lix[r * CAP_ + cg + 16]; }
        if (h2v) { a2 = lsc[r * CAP_ + cg + 32]; x2 = lix[r * CAP_ + cg + 32]; }
        int r0 = 0, r1 = 0, r2 = 0;
        for (int t = 0; t < len; ++t) {
            float bs = lsc[r * CAP_ + t];
            int   bi = lix[r * CAP_ + t];
            r0 += (bs < a0) || (bs == a0 && bi < x0);
            r1 += (bs < a1) || (bs == a1 && bi < x1);
            r2 += (bs < a2) || (bs == a2 && bi < x2);
        }
        const size_t grow = (size_t)(b * N_ + rowBase + r);
        if (h0  && r0 < KP_) idx24[grow * KP_ + r0] = x0;
        if (h1  && r1 < KP_) idx24[grow * KP_ + r1] = x1;
        if (h2v && r2 < KP_) idx24[grow * KP_ + r2] = x2;
    }
}

// ---------------------------------------------------------------------------
// Kernel 3: f64 re-rank of the 24 candidates with the exact reference formula
// ---------------------------------------------------------------------------
__global__ __launch_bounds__(256) void k_rerank(const float* __restrict__ x,
                                                const double* __restrict__ sq64,
                                                const int* __restrict__ idx24,
                                                int* __restrict__ idx20) {
    __shared__ double dd[8 * KP_];
    __shared__ int    ii[8 * KP_];
    const int tid = threadIdx.x;
    const int rl = tid >> 5;       // row-in-block 0..7
    const int lane = tid & 31;
    const int row = blockIdx.x * 8 + rl;
    const int b = row >> 12, n = row & (N_ - 1);
    const int cand = (lane < KP_) ? idx24[(size_t)row * KP_ + lane] : 0;
    const float* __restrict__ xb = x + (size_t)b * C_ * N_;
    double dot = 0.0;
    #pragma unroll 4
    for (int c = 0; c < C_; ++c) {
        double xn = (double)xb[(size_t)c * N_ + n];
        double xj = (double)xb[(size_t)c * N_ + cand];
        dot = fma(xn, xj, dot);
    }
    double d2 = (sq64[row] + sq64[b * N_ + cand]) - 2.0 * dot;
    if (lane < KP_) { dd[rl * KP_ + lane] = d2; ii[rl * KP_ + lane] = cand; }
    __syncthreads();
    if (lane < KP_) {
        int rank = 0;
        for (int t = 0; t < KP_; ++t) {
            double od = dd[rl * KP_ + t];
            int oi = ii[rl * KP_ + t];
            if (od < d2 || (od == d2 && oi < cand)) ++rank;
        }
        if (rank < KNN_) idx20[(size_t)row * KNN_ + rank] = cand;
    }
}

// ---------------------------------------------------------------------------
// Kernel 4: BN batch stats (sum, sumsq per channel)
// ---------------------------------------------------------------------------
__global__ __launch_bounds__(256) void k_stats(const float* __restrict__ u,
                                               const float* __restrict__ v,
                                               const float* __restrict__ bias,
                                               const int* __restrict__ idx20,
                                               float* __restrict__ psum,
                                               float* __restrict__ psq) {
    __shared__ float red[512];
    const int tid = threadIdx.x;
    const int o = tid & 63, w = tid >> 6;
    const int base = blockIdx.x * 128;          // 128 rows per block, same batch
    const int b = base >> 12;
    const float bo = bias[o];
    float s = 0.f, s2 = 0.f;
    for (int nn = w; nn < 128; nn += 4) {
        const int row = base + nn;
        const float uo = u[(size_t)row * 64 + o] + bo;
        const int* ip = idx20 + (size_t)row * KNN_;
        #pragma unroll 4
        for (int k = 0; k < KNN_; ++k) {
            int j = ip[k];
            float y = uo + v[((size_t)b * N_ + j) * 64 + o];
            s += y;
            s2 = fmaf(y, y, s2);
        }
    }
    red[tid] = s;
    red[256 + tid] = s2;
    __syncthreads();
    if (tid < 64) {
        float t  = red[o] + red[64 + o] + red[128 + o] + red[192 + o];
        float t2 = red[256 + o] + red[320 + o] + red[384 + o] + red[448 + o];
        psum[blockIdx.x * 64 + o] = t;
        psq[blockIdx.x * 64 + o]  = t2;
    }
}

// Kernel 4b: finalize BN -> per-channel scale/shift
__global__ void k_bn(const float* __restrict__ psum, const float* __restrict__ psq,
                     const float* __restrict__ gamma, const float* __restrict__ beta,
                     float* __restrict__ scsh) {
    const int o = threadIdx.x;
    if (o >= 64) return;
    float s = 0.f, s2 = 0.f;
    for (int i = 0; i < 256; ++i) { s += psum[i * 64 + o]; s2 += psq[i * 64 + o]; }
    const float cnt = (float)B_ * (float)N_ * (float)KNN_;
    float mean = s / cnt;
    float var = s2 / cnt - mean * mean;
    float scale = gamma[o] / sqrtf(var + 1e-5f);
    float shift = beta[o] - mean * scale;
    scsh[o] = scale;
    scsh[64 + o] = shift;
}

// ---------------------------------------------------------------------------
// Kernel 5: out[b,o,n] = lrelu(scale*extreme_k(y) + shift)
// ---------------------------------------------------------------------------
__global__ __launch_bounds__(256) void k_final(const float* __restrict__ u,
                                               const float* __restrict__ v,
                                               const float* __restrict__ bias,
                                               const int* __restrict__ idx20,
                                               const float* __restrict__ scsh,
                                               float* __restrict__ out) {
    __shared__ float tr[64 * 129];
    const int tid = threadIdx.x;
    const int o = tid & 63, w = tid >> 6;
    const int base = blockIdx.x * 128;
    const int b = base >> 12;
    const int nbase = base & (N_ - 1);
    const float bo = bias[o];
    const float sc = scsh[o];
    const float sh = scsh[64 + o];
    for (int nn = w; nn < 128; nn += 4) {
        const int row = base + nn;
        const float uo = u[(size_t)row * 64 + o] + bo;
        const int* ip = idx20 + (size_t)row * KNN_;
        float mx = -INFINITY, mn = INFINITY;
        #pragma unroll 4
        for (int k = 0; k < KNN_; ++k) {
            int j = ip[k];
            float y = uo + v[((size_t)b * N_ + j) * 64 + o];
            mx = fmaxf(mx, y);
            mn = fminf(mn, y);
        }
        float best = (sc >= 0.f) ? mx : mn;
        float z = fmaf(best, sc, sh);
        tr[o * 129 + nn] = (z >= 0.f) ? z : 0.2f * z;
    }
    __syncthreads();
    for (int k = 0; k < 32; ++k) {      // 64*128 / 256
        int i = tid + k * 256;
        int o2 = i >> 7, n2 = i & 127;
        out[((size_t)b * 64 + o2) * N_ + nbase + n2] = tr[o2 * 129 + n2];
    }
}

// ---------------------------------------------------------------------------
extern "C" void kernel_launch(void* const* d_in, const int* in_sizes, int n_in,
                              void* d_out, int out_size, void* d_ws, size_t ws_size,
                              hipStream_t stream) {
    const float* x     = (const float*)d_in[0];
    const float* W     = (const float*)d_in[1];
    const float* bias  = (const float*)d_in[2];
    const float* gamma = (const float*)d_in[3];
    const float* beta  = (const float*)d_in[4];
    float* out = (float*)d_out;

    char* ws = (char*)d_ws;
    float*  u     = (float*)(ws + 0);           //  8,388,608 B
    float*  v     = (float*)(ws + 8388608);     //  8,388,608 B
    float*  sq32  = (float*)(ws + 16777216);    //    131,072 B
    double* sq64  = (double*)(ws + 16908288);   //    262,144 B
    int*    idx24 = (int*)(ws + 17170432);      //  3,145,728 B
    int*    idx20 = (int*)(ws + 20316160);      //  2,621,440 B
    float*  psum  = (float*)(ws + 22937600);    //     65,536 B
    float*  psq   = (float*)(ws + 23003136);    //     65,536 B
    float*  scsh  = (float*)(ws + 23068672);    //        512 B

    hipLaunchKernelGGL(k_uv,     dim3(8192), dim3(256), 0, stream, x, W, u, v, sq32, sq64);
    hipLaunchKernelGGL(k_knn,    dim3(512),  dim3(128), 0, stream, x, sq32, idx24);
    hipLaunchKernelGGL(k_rerank, dim3(4096), dim3(256), 0, stream, x, sq64, idx24, idx20);
    hipLaunchKernelGGL(k_stats,  dim3(256),  dim3(256), 0, stream, u, v, bias, idx20, psum, psq);
    hipLaunchKernelGGL(k_bn,     dim3(1),    dim3(64),  0, stream, psum, psq, gamma, beta, scsh);
    hipLaunchKernelGGL(k_final,  dim3(256),  dim3(256), 0, stream, u, v, bias, idx20, scsh, out);
}

// Round 3
// 678.244 us; speedup vs baseline: 3.4195x; 2.7062x over previous
//
#include <hip/hip_runtime.h>
#include <math.h>

#define B_    8
#define C_    64
#define N_    4096
#define OUT_  64
#define KNN_  20
#define KP_   24     // candidates kept per row for f64 rerank

// histogram selection params
#define NB_   128            // bins
#define HLO_  (-64.0f)
#define HHI_  32.0f
#define HSC_  (4.0f/3.0f)    // NB_/(HHI_-HLO_)
#define CAP2_ 80             // per-query collection capacity

typedef __attribute__((ext_vector_type(8)))  short bf16x8;
typedef __attribute__((ext_vector_type(16))) float f32x16;

__device__ __forceinline__ unsigned short bf16rtn(float f) {
    unsigned u = __float_as_uint(f);
    u += 0x7FFFu + ((u >> 16) & 1u);
    return (unsigned short)(u >> 16);
}

__device__ __forceinline__ void gld16(const void* g, void* l) {
    __builtin_amdgcn_global_load_lds((const __attribute__((address_space(1))) void*)g,
                                     (__attribute__((address_space(3))) void*)l, 16, 0, 0);
}

// ---------------------------------------------------------------------------
// Kernel 1: per-point projections u = (W1-W2)·p, v = W2·p, and squared norms
// ---------------------------------------------------------------------------
__global__ __launch_bounds__(256) void k_uv(const float* __restrict__ x,
                                            const float* __restrict__ W,
                                            float* __restrict__ u,
                                            float* __restrict__ v,
                                            float* __restrict__ sq32,
                                            double* __restrict__ sq64) {
    __shared__ float Wd[64 * 64];   // [c][o] = W1 - W2
    __shared__ float W2s[64 * 64];  // [c][o] = W2
    const int tid = threadIdx.x;
    for (int k = 0; k < 16; ++k) {
        int i = tid + k * 256;
        int o = i & 63, c = i >> 6;
        float w1 = W[o * 128 + c];
        float w2 = W[o * 128 + 64 + c];
        Wd[c * 64 + o]  = w1 - w2;
        W2s[c * 64 + o] = w2;
    }
    __syncthreads();
    const int o = tid & 63, w = tid >> 6;
    const int row = blockIdx.x * 4 + w;         // < 32768
    const int b = row >> 12, n = row & (N_ - 1);
    const float* xp = x + (size_t)b * C_ * N_ + n;
    float ua = 0.f, va = 0.f;
    double sq = 0.0;
    for (int c = 0; c < 64; ++c) {
        float xc = xp[(size_t)c * N_];          // broadcast across the wave
        ua = fmaf(Wd[c * 64 + o], xc, ua);
        va = fmaf(W2s[c * 64 + o], xc, va);
        double xd = (double)xc;
        sq = fma(xd, xd, sq);
    }
    u[(size_t)row * 64 + o] = ua;
    v[(size_t)row * 64 + o] = va;
    if (o == 0) { sq64[row] = sq; sq32[row] = (float)sq; }
}

// ---------------------------------------------------------------------------
// Kernel 1b: bf16 hi/lo split of x, packed MFMA-ready:
// xh/xl[(b*8+g)*N + n] = 16B unit holding channels 8g..8g+7 (bf16) of point n.
// ---------------------------------------------------------------------------
__global__ __launch_bounds__(256) void k_pack(const float* __restrict__ x,
                                              uint4* __restrict__ xh,
                                              uint4* __restrict__ xl) {
    const int b  = blockIdx.x >> 6;
    const int nb = (blockIdx.x & 63) << 6;
    const int nl = threadIdx.x & 63, gs = threadIdx.x >> 6;   // gs 0..3
    for (int r = 0; r < 2; ++r) {
        const int g = r * 4 + gs;
        const float* xp = x + ((size_t)(b * 64 + g * 8)) * N_ + nb + nl;
        unsigned hw[4], lw[4];
        #pragma unroll
        for (int w = 0; w < 4; ++w) {
            float x0 = xp[(size_t)(2 * w) * N_];
            float x1 = xp[(size_t)(2 * w + 1) * N_];
            unsigned short h0 = bf16rtn(x0), h1 = bf16rtn(x1);
            float f0 = __uint_as_float((unsigned)h0 << 16);
            float f1 = __uint_as_float((unsigned)h1 << 16);
            unsigned short l0 = bf16rtn(x0 - f0), l1 = bf16rtn(x1 - f1);
            hw[w] = (unsigned)h0 | ((unsigned)h1 << 16);
            lw[w] = (unsigned)l0 | ((unsigned)l1 << 16);
        }
        size_t ui = (size_t)(b * 8 + g) * N_ + nb + nl;
        xh[ui] = make_uint4(hw[0], hw[1], hw[2], hw[3]);
        xl[ui] = make_uint4(lw[0], lw[1], lw[2], lw[3]);
    }
}

// ---------------------------------------------------------------------------
// Kernel 2: MFMA Gram + per-query top-24 via two-pass histogram selection.
// Block: 64 queries (2 sets of 32) x 4 waves (each wave owns a 1024-candidate
// j-quarter). dot = Ah·Bh + Ah·Bl + Al·Bh (bf16 split), acc f32.
// Pass A: histogram scores (gated s < 32) -> per-query 24th-best bin T.
// Pass B: recompute, collect bin <= T+1 into shared list, exact rank -> 24.
// ---------------------------------------------------------------------------
__global__ __launch_bounds__(256) void k_knn(const uint4* __restrict__ xh,
                                             const uint4* __restrict__ xl,
                                             const float* __restrict__ sq32,
                                             int* __restrict__ idx24) {
    extern __shared__ char smem[];
    // 0     : staging, 4 waves x 9216 (Ah 4096 | Al 4096 | sq 1024)
    // 36864 : union { hist u32[64*128] (32KB) ; list float2[64*80] (40KB) }
    // 77824 : cnt u32[64];  78080 : edge int[64];  total 78336
    unsigned* hist = (unsigned*)(smem + 36864);
    float2*   list = (float2*)(smem + 36864);
    unsigned* cnt  = (unsigned*)(smem + 77824);
    int*      edge = (int*)(smem + 78080);

    const int tid = threadIdx.x;
    const int b   = blockIdx.x >> 6;
    const int qb  = (blockIdx.x & 63) << 6;
    const int wid = tid >> 6, l = tid & 63, h = l >> 5, ql = l & 31;
    char* stg = smem + wid * 9216;
    const int jq = wid * 1024;
    const uint4* xhb = xh + (size_t)b * 8 * N_;
    const uint4* xlb = xl + (size_t)b * 8 * N_;
    const float* sqb = sq32 + b * N_;

    for (int i = tid; i < 64 * NB_; i += 256) hist[i] = 0u;

    // B fragments (queries), persistent: lane l -> col ql, k = 16kk + 8h + r
    bf16x8 Bh[2][4], Bl[2][4];
    #pragma unroll
    for (int s = 0; s < 2; ++s)
        #pragma unroll
        for (int kk = 0; kk < 4; ++kk) {
            size_t uu = (size_t)(2 * kk + h) * N_ + qb + s * 32 + ql;
            Bh[s][kk] = *(const bf16x8*)&xhb[uu];
            Bl[s][kk] = *(const bf16x8*)&xlb[uu];
        }
    __syncthreads();   // hist zeroed before pass-A atomics

    auto STAGE = [&](int jb) {
        #pragma unroll
        for (int p = 0; p < 4; ++p) {
            size_t uu = (size_t)(2 * p + h) * N_ + jb + ql;
            gld16(&xhb[uu], stg + p * 1024);
            gld16(&xlb[uu], stg + 4096 + p * 1024);
        }
        gld16(sqb + jb + l * 4, stg + 8192);   // lanes 8..63 stage unused bytes
    };

    auto PASSLOOP = [&](int pass, int e0, int e1) {
        STAGE(jq);
        #pragma unroll 1
        for (int t = 0; t < 32; ++t) {
            const int jb = jq + t * 32;
            asm volatile("s_waitcnt vmcnt(0)" ::: "memory");
            __builtin_amdgcn_sched_barrier(0);
            bf16x8 Ah[4], Al[4];
            #pragma unroll
            for (int kk = 0; kk < 4; ++kk) {
                Ah[kk] = *(const bf16x8*)(stg + kk * 1024 + l * 16);
                Al[kk] = *(const bf16x8*)(stg + 4096 + kk * 1024 + l * 16);
            }
            float sqs[16];
            #pragma unroll
            for (int rq = 0; rq < 4; ++rq) {
                float4 vv = *(const float4*)(stg + 8192 + (8 * rq + 4 * h) * 4);
                sqs[rq * 4 + 0] = vv.x; sqs[rq * 4 + 1] = vv.y;
                sqs[rq * 4 + 2] = vv.z; sqs[rq * 4 + 3] = vv.w;
            }
            asm volatile("s_waitcnt lgkmcnt(0)" ::: "memory");
            __builtin_amdgcn_sched_barrier(0);
            if (t < 31) STAGE(jb + 32);

            f32x16 a0, a1;
            #pragma unroll
            for (int i = 0; i < 16; ++i) { a0[i] = 0.f; a1[i] = 0.f; }
            #pragma unroll
            for (int kk = 0; kk < 4; ++kk) {
                a0 = __builtin_amdgcn_mfma_f32_32x32x16_bf16(Ah[kk], Bh[0][kk], a0, 0, 0, 0);
                a1 = __builtin_amdgcn_mfma_f32_32x32x16_bf16(Ah[kk], Bh[1][kk], a1, 0, 0, 0);
                a0 = __builtin_amdgcn_mfma_f32_32x32x16_bf16(Ah[kk], Bl[0][kk], a0, 0, 0, 0);
                a1 = __builtin_amdgcn_mfma_f32_32x32x16_bf16(Ah[kk], Bl[1][kk], a1, 0, 0, 0);
                a0 = __builtin_amdgcn_mfma_f32_32x32x16_bf16(Al[kk], Bh[0][kk], a0, 0, 0, 0);
                a1 = __builtin_amdgcn_mfma_f32_32x32x16_bf16(Al[kk], Bh[1][kk], a1, 0, 0, 0);
            }
            #pragma unroll
            for (int s = 0; s < 2; ++s) {
                const int qq = s * 32 + ql;
                const int eT = s ? e1 : e0;
                #pragma unroll
                for (int r = 0; r < 16; ++r) {
                    float av = s ? a1[r] : a0[r];
                    float sc = fmaf(-2.0f, av, sqs[r]);
                    if (sc < HHI_) {
                        int bin = (int)((sc - HLO_) * HSC_);
                        bin = bin < 0 ? 0 : bin;
                        if (pass == 0) {
                            atomicAdd(&hist[qq * NB_ + bin], 1u);
                        } else if (bin <= eT) {
                            unsigned slot = atomicAdd(&cnt[qq], 1u);
                            if (slot < CAP2_) {
                                int j = jb + (r & 3) + 8 * (r >> 2) + 4 * h;
                                list[qq * CAP2_ + slot] = make_float2(sc, __int_as_float(j));
                            }
                        }
                    }
                }
            }
        }
    };

    PASSLOOP(0, 0, 0);
    __syncthreads();                    // all histogram atomics done
    if (tid < 64) {
        int T = NB_ - 1, acc = 0;
        #pragma unroll 1
        for (int bin = 0; bin < NB_; ++bin) {
            acc += (int)hist[tid * NB_ + bin];
            if (acc >= KP_) { T = bin; break; }
        }
        edge[tid] = T;
        cnt[tid] = 0u;
    }
    __syncthreads();                    // edges ready, hist area reusable
    const int e0 = edge[ql] + 1, e1 = edge[32 + ql] + 1;   // +1 margin
    PASSLOOP(1, e0, e1);
    __syncthreads();                    // all appends done

    // exact rank-select top-24 by (score, idx); deterministic output
    const int qq2 = tid >> 2, part = tid & 3;
    int cn = (int)cnt[qq2]; cn = cn > CAP2_ ? CAP2_ : cn;
    const size_t row = (size_t)b * N_ + qb + qq2;
    for (int e = part; e < cn; e += 4) {
        float2 me = list[qq2 * CAP2_ + e];
        float ms = me.x; int mj = __float_as_int(me.y);
        int rk = 0;
        for (int o = 0; o < cn; ++o) {
            float2 ot = list[qq2 * CAP2_ + o];
            rk += (ot.x < ms) || (ot.x == ms && __float_as_int(ot.y) < mj);
        }
        if (rk < KP_) idx24[row * KP_ + rk] = mj;
    }
}

// ---------------------------------------------------------------------------
// Kernel 3: f64 re-rank of the 24 candidates with the exact reference formula
// ---------------------------------------------------------------------------
__global__ __launch_bounds__(256) void k_rerank(const float* __restrict__ x,
                                                const double* __restrict__ sq64,
                                                const int* __restrict__ idx24,
                                                int* __restrict__ idx20) {
    __shared__ double dd[8 * KP_];
    __shared__ int    ii[8 * KP_];
    const int tid = threadIdx.x;
    const int rl = tid >> 5;       // row-in-block 0..7
    const int lane = tid & 31;
    const int row = blockIdx.x * 8 + rl;
    const int b = row >> 12, n = row & (N_ - 1);
    const int cand = (lane < KP_) ? (idx24[(size_t)row * KP_ + lane] & (N_ - 1)) : 0;
    const float* __restrict__ xb = x + (size_t)b * C_ * N_;
    double dot = 0.0;
    #pragma unroll 4
    for (int c = 0; c < C_; ++c) {
        double xn = (double)xb[(size_t)c * N_ + n];
        double xj = (double)xb[(size_t)c * N_ + cand];
        dot = fma(xn, xj, dot);
    }
    double d2 = (sq64[row] + sq64[b * N_ + cand]) - 2.0 * dot;
    if (lane < KP_) { dd[rl * KP_ + lane] = d2; ii[rl * KP_ + lane] = cand; }
    __syncthreads();
    if (lane < KP_) {
        int rank = 0;
        for (int t = 0; t < KP_; ++t) {
            double od = dd[rl * KP_ + t];
            int oi = ii[rl * KP_ + t];
            if (od < d2 || (od == d2 && oi < cand)) ++rank;
        }
        if (rank < KNN_) idx20[(size_t)row * KNN_ + rank] = cand;
    }
}

// ---------------------------------------------------------------------------
// Kernel 4: BN batch stats (sum, sumsq per channel)
// ---------------------------------------------------------------------------
__global__ __launch_bounds__(256) void k_stats(const float* __restrict__ u,
                                               const float* __restrict__ v,
                                               const float* __restrict__ bias,
                                               const int* __restrict__ idx20,
                                               float* __restrict__ psum,
                                               float* __restrict__ psq) {
    __shared__ float red[512];
    const int tid = threadIdx.x;
    const int o = tid & 63, w = tid >> 6;
    const int base = blockIdx.x * 128;          // 128 rows per block, same batch
    const int b = base >> 12;
    const float bo = bias[o];
    float s = 0.f, s2 = 0.f;
    for (int nn = w; nn < 128; nn += 4) {
        const int row = base + nn;
        const float uo = u[(size_t)row * 64 + o] + bo;
        const int* ip = idx20 + (size_t)row * KNN_;
        #pragma unroll 4
        for (int k = 0; k < KNN_; ++k) {
            int j = ip[k];
            float y = uo + v[((size_t)b * N_ + j) * 64 + o];
            s += y;
            s2 = fmaf(y, y, s2);
        }
    }
    red[tid] = s;
    red[256 + tid] = s2;
    __syncthreads();
    if (tid < 64) {
        float t  = red[o] + red[64 + o] + red[128 + o] + red[192 + o];
        float t2 = red[256 + o] + red[320 + o] + red[384 + o] + red[448 + o];
        psum[blockIdx.x * 64 + o] = t;
        psq[blockIdx.x * 64 + o]  = t2;
    }
}

// Kernel 4b: finalize BN -> per-channel scale/shift
__global__ void k_bn(const float* __restrict__ psum, const float* __restrict__ psq,
                     const float* __restrict__ gamma, const float* __restrict__ beta,
                     float* __restrict__ scsh) {
    const int o = threadIdx.x;
    if (o >= 64) return;
    float s = 0.f, s2 = 0.f;
    for (int i = 0; i < 256; ++i) { s += psum[i * 64 + o]; s2 += psq[i * 64 + o]; }
    const float cnt = (float)B_ * (float)N_ * (float)KNN_;
    float mean = s / cnt;
    float var = s2 / cnt - mean * mean;
    float scale = gamma[o] / sqrtf(var + 1e-5f);
    float shift = beta[o] - mean * scale;
    scsh[o] = scale;
    scsh[64 + o] = shift;
}

// ---------------------------------------------------------------------------
// Kernel 5: out[b,o,n] = lrelu(scale*extreme_k(y) + shift)
// ---------------------------------------------------------------------------
__global__ __launch_bounds__(256) void k_final(const float* __restrict__ u,
                                               const float* __restrict__ v,
                                               const float* __restrict__ bias,
                                               const int* __restrict__ idx20,
                                               const float* __restrict__ scsh,
                                               float* __restrict__ out) {
    __shared__ float tr[64 * 129];
    const int tid = threadIdx.x;
    const int o = tid & 63, w = tid >> 6;
    const int base = blockIdx.x * 128;
    const int b = base >> 12;
    const int nbase = base & (N_ - 1);
    const float bo = bias[o];
    const float sc = scsh[o];
    const float sh = scsh[64 + o];
    for (int nn = w; nn < 128; nn += 4) {
        const int row = base + nn;
        const float uo = u[(size_t)row * 64 + o] + bo;
        const int* ip = idx20 + (size_t)row * KNN_;
        float mx = -INFINITY, mn = INFINITY;
        #pragma unroll 4
        for (int k = 0; k < KNN_; ++k) {
            int j = ip[k];
            float y = uo + v[((size_t)b * N_ + j) * 64 + o];
            mx = fmaxf(mx, y);
            mn = fminf(mn, y);
        }
        float best = (sc >= 0.f) ? mx : mn;
        float z = fmaf(best, sc, sh);
        tr[o * 129 + nn] = (z >= 0.f) ? z : 0.2f * z;
    }
    __syncthreads();
    for (int k = 0; k < 32; ++k) {      // 64*128 / 256
        int i = tid + k * 256;
        int o2 = i >> 7, n2 = i & 127;
        out[((size_t)b * 64 + o2) * N_ + nbase + n2] = tr[o2 * 129 + n2];
    }
}

// ---------------------------------------------------------------------------
extern "C" void kernel_launch(void* const* d_in, const int* in_sizes, int n_in,
                              void* d_out, int out_size, void* d_ws, size_t ws_size,
                              hipStream_t stream) {
    const float* x     = (const float*)d_in[0];
    const float* W     = (const float*)d_in[1];
    const float* bias  = (const float*)d_in[2];
    const float* gamma = (const float*)d_in[3];
    const float* beta  = (const float*)d_in[4];
    float* out = (float*)d_out;

    char* ws = (char*)d_ws;
    float*  u     = (float*)(ws + 0);           //  8,388,608 B
    float*  v     = (float*)(ws + 8388608);     //  8,388,608 B
    float*  sq32  = (float*)(ws + 16777216);    //    131,072 B
    double* sq64  = (double*)(ws + 16908288);   //    262,144 B
    int*    idx24 = (int*)(ws + 17170432);      //  3,145,728 B
    int*    idx20 = (int*)(ws + 20316160);      //  2,621,440 B
    float*  psum  = (float*)(ws + 22937600);    //     65,536 B
    float*  psq   = (float*)(ws + 23003136);    //     65,536 B
    float*  scsh  = (float*)(ws + 23068672);    //        512 B
    uint4*  xh    = (uint4*)(ws + 23069184);    //  4,194,304 B
    uint4*  xl    = (uint4*)(ws + 27263488);    //  4,194,304 B  (end ~30 MB)

    hipLaunchKernelGGL(k_uv,     dim3(8192), dim3(256), 0,     stream, x, W, u, v, sq32, sq64);
    hipLaunchKernelGGL(k_pack,   dim3(512),  dim3(256), 0,     stream, x, xh, xl);
    hipLaunchKernelGGL(k_knn,    dim3(512),  dim3(256), 78336, stream, xh, xl, sq32, idx24);
    hipLaunchKernelGGL(k_rerank, dim3(4096), dim3(256), 0,     stream, x, sq64, idx24, idx20);
    hipLaunchKernelGGL(k_stats,  dim3(256),  dim3(256), 0,     stream, u, v, bias, idx20, psum, psq);
    hipLaunchKernelGGL(k_bn,     dim3(1),    dim3(64),  0,     stream, psum, psq, gamma, beta, scsh);
    hipLaunchKernelGGL(k_final,  dim3(256),  dim3(256), 0,     stream, u, v, bias, idx20, scsh, out);
}

// Round 5
// 451.552 us; speedup vs baseline: 5.1362x; 1.5020x over previous
//
#include <hip/hip_runtime.h>
#include <math.h>

#define B_    8
#define C_    64
#define N_    4096
#define OUT_  64
#define KNN_  20
#define KP_   28     // candidates kept per row for f64 rerank (slack for hi-only bf16 Gram)

// histogram selection params (128 bins over [-80, 40), width 0.9375)
#define NB_   128
#define HLO_  (-80.0f)
#define HHI_  40.0f
#define HSC_  (128.0f/120.0f)
#define CAPB_ 80             // per-query collection capacity (>=7 sigma over ~33 expected)

typedef __attribute__((ext_vector_type(8)))  short bf16x8;
typedef __attribute__((ext_vector_type(16))) float f32x16;

__device__ __forceinline__ unsigned short bf16rtn(float f) {
    unsigned u = __float_as_uint(f);
    u += 0x7FFFu + ((u >> 16) & 1u);
    return (unsigned short)(u >> 16);
}

__device__ __forceinline__ void gld16(const void* g, void* l) {
    __builtin_amdgcn_global_load_lds((const __attribute__((address_space(1))) void*)g,
                                     (__attribute__((address_space(3))) void*)l, 16, 0, 0);
}

// ---------------------------------------------------------------------------
// Kernel 1: fused prep. Per block: 64-point tile of one batch.
//  - u = (W1-W2)·p + bias, v = W2·p      (bias pre-folded into u)
//  - xh = bf16(hi) pack, MFMA-frag-ready  [b][g][n] 16B units
//  - sq32/sq64 = |p|^2
// ---------------------------------------------------------------------------
__global__ __launch_bounds__(256) void k_prep(const float* __restrict__ x,
                                              const float* __restrict__ W,
                                              const float* __restrict__ bias,
                                              float* __restrict__ u,
                                              float* __restrict__ v,
                                              float* __restrict__ sq32,
                                              double* __restrict__ sq64,
                                              uint4* __restrict__ xh) {
    __shared__ float xs[64][65];     // [c][n]
    __shared__ float Wd[64 * 64];    // [c][o] = W1 - W2
    __shared__ float W2s[64 * 64];   // [c][o] = W2
    const int tid = threadIdx.x;
    const int b = blockIdx.x >> 6, nb = (blockIdx.x & 63) << 6;

    for (int k = 0; k < 16; ++k) {
        int i = tid + k * 256;
        int o = i & 63, c = i >> 6;
        float w1 = W[o * 128 + c];
        float w2 = W[o * 128 + 64 + c];
        Wd[c * 64 + o]  = w1 - w2;
        W2s[c * 64 + o] = w2;
    }
    for (int k = 0; k < 16; ++k) {
        int i = tid + k * 256;
        int c = i >> 6, n = i & 63;
        xs[c][n] = x[((size_t)b * 64 + c) * N_ + nb + n];
    }
    __syncthreads();

    const int o = tid & 63, w = tid >> 6;
    // --- u, v: 16 rows per thread, register accumulation ---
    float uacc[16], vacc[16];
    #pragma unroll
    for (int i = 0; i < 16; ++i) { uacc[i] = 0.f; vacc[i] = 0.f; }
    for (int c = 0; c < 64; ++c) {
        float wd = Wd[c * 64 + o], w2 = W2s[c * 64 + o];
        #pragma unroll
        for (int i = 0; i < 16; ++i) {
            float xc = xs[c][w * 16 + i];        // broadcast within wave
            uacc[i] = fmaf(wd, xc, uacc[i]);
            vacc[i] = fmaf(w2, xc, vacc[i]);
        }
    }
    const float bo = bias[o];
    #pragma unroll
    for (int i = 0; i < 16; ++i) {
        size_t row = (size_t)b * N_ + nb + w * 16 + i;
        u[row * 64 + o] = uacc[i] + bo;
        v[row * 64 + o] = vacc[i];
    }

    // --- pack xh (hi bf16 only): 2 channel-groups per thread ---
    {
        const int nl = tid & 63;
        #pragma unroll
        for (int gg = 0; gg < 2; ++gg) {
            const int g = (tid >> 6) + gg * 4;   // 0..7
            unsigned hw[4];
            #pragma unroll
            for (int e = 0; e < 4; ++e) {
                float x0 = xs[g * 8 + 2 * e][nl];
                float x1 = xs[g * 8 + 2 * e + 1][nl];
                hw[e] = (unsigned)bf16rtn(x0) | ((unsigned)bf16rtn(x1) << 16);
            }
            xh[(size_t)(b * 8 + g) * N_ + nb + nl] = make_uint4(hw[0], hw[1], hw[2], hw[3]);
        }
    }

    // --- squared norms (f64 exact) ---
    if (tid < 64) {
        const int n = tid;
        double sq = 0.0;
        for (int c = 0; c < 64; ++c) {
            double xd = (double)xs[c][n];
            sq = fma(xd, xd, sq);
        }
        sq64[(size_t)b * N_ + nb + n] = sq;
        sq32[(size_t)b * N_ + nb + n] = (float)sq;
    }
}

// ---------------------------------------------------------------------------
// Kernel 2: MFMA Gram (bf16 hi x hi) + per-query top-28 via 2-pass histogram.
// 512 threads = 8 waves; block owns 64 queries; each wave owns a 512-cand
// j-eighth (16 tiles of 32). Pass A: histogram approx scores. Pass B:
// collect bins <= T+1, exact (score,idx) rank-select -> top-28.
// ---------------------------------------------------------------------------
__global__ __launch_bounds__(512, 4) void k_knn(const uint4* __restrict__ xh,
                                                const float* __restrict__ sq32,
                                                int* __restrict__ idx24) {
    extern __shared__ char smem[];
    // 0     : staging, 8 waves x 4096 (Ah)
    // 32768 : union { hist u32[64*128] (32KB) ; list float2[64*80] (40KB) }
    // 73728 : cnt u32[64];  73984 : edge int[64];  total 74240
    unsigned* hist = (unsigned*)(smem + 32768);
    float2*   list = (float2*)(smem + 32768);
    unsigned* cnt  = (unsigned*)(smem + 73728);
    int*      edge = (int*)(smem + 73984);

    const int tid = threadIdx.x;
    const int b   = blockIdx.x >> 6;
    const int qb  = (blockIdx.x & 63) << 6;
    const int wid = tid >> 6, l = tid & 63, h = l >> 5, ql = l & 31;
    char* stg = smem + wid * 4096;
    const int jq = wid * 512;
    const uint4* xhb = xh + (size_t)b * 8 * N_;
    const float* sqb = sq32 + b * N_;

    for (int i = tid; i < 64 * NB_; i += 512) hist[i] = 0u;

    // B fragments (queries, hi only), persistent in regs: lane -> col ql(+32s)
    bf16x8 Bh[2][4];
    #pragma unroll
    for (int s = 0; s < 2; ++s)
        #pragma unroll
        for (int kk = 0; kk < 4; ++kk)
            Bh[s][kk] = *(const bf16x8*)&xhb[(size_t)(2 * kk + h) * N_ + qb + s * 32 + ql];
    __syncthreads();   // hist zeroed

    auto STAGE = [&](int jb) {
        #pragma unroll
        for (int p = 0; p < 4; ++p)
            gld16(&xhb[(size_t)(2 * p + h) * N_ + jb + ql], stg + p * 1024);
    };

    auto PASSLOOP = [&](int pass, int e0, int e1) {
        STAGE(jq);
        #pragma unroll 1
        for (int t = 0; t < 16; ++t) {
            const int jb = jq + t * 32;
            asm volatile("s_waitcnt vmcnt(0)" ::: "memory");
            __builtin_amdgcn_sched_barrier(0);
            bf16x8 Ah[4];
            #pragma unroll
            for (int kk = 0; kk < 4; ++kk)
                Ah[kk] = *(const bf16x8*)(stg + kk * 1024 + l * 16);
            // sq of the 16 j's this lane will score (global, L1/L2-hot)
            float4 q0 = *(const float4*)(sqb + jb + 4 * h);
            float4 q1 = *(const float4*)(sqb + jb + 8 + 4 * h);
            float4 q2 = *(const float4*)(sqb + jb + 16 + 4 * h);
            float4 q3 = *(const float4*)(sqb + jb + 24 + 4 * h);
            asm volatile("s_waitcnt lgkmcnt(0)" ::: "memory");
            __builtin_amdgcn_sched_barrier(0);
            if (t < 15) STAGE(jb + 32);

            f32x16 a0, a1;
            #pragma unroll
            for (int i = 0; i < 16; ++i) { a0[i] = 0.f; a1[i] = 0.f; }
            #pragma unroll
            for (int kk = 0; kk < 4; ++kk) {
                a0 = __builtin_amdgcn_mfma_f32_32x32x16_bf16(Ah[kk], Bh[0][kk], a0, 0, 0, 0);
                a1 = __builtin_amdgcn_mfma_f32_32x32x16_bf16(Ah[kk], Bh[1][kk], a1, 0, 0, 0);
            }
            float sq16[16];
            sq16[0]=q0.x; sq16[1]=q0.y; sq16[2]=q0.z; sq16[3]=q0.w;
            sq16[4]=q1.x; sq16[5]=q1.y; sq16[6]=q1.z; sq16[7]=q1.w;
            sq16[8]=q2.x; sq16[9]=q2.y; sq16[10]=q2.z; sq16[11]=q2.w;
            sq16[12]=q3.x; sq16[13]=q3.y; sq16[14]=q3.z; sq16[15]=q3.w;

            #pragma unroll
            for (int s = 0; s < 2; ++s) {
                const int qq = s * 32 + ql;
                const int eT = s ? e1 : e0;
                #pragma unroll
                for (int r = 0; r < 16; ++r) {
                    float av = s ? a1[r] : a0[r];
                    float sc = fmaf(-2.0f, av, sq16[r]);
                    if (sc < HHI_) {
                        int bin = (int)((sc - HLO_) * HSC_);
                        bin = bin < 0 ? 0 : bin;
                        if (pass == 0) {
                            atomicAdd(&hist[qq * NB_ + bin], 1u);
                        } else if (bin <= eT) {
                            unsigned slot = atomicAdd(&cnt[qq], 1u);
                            if (slot < CAPB_) {
                                int j = jb + (r & 3) + 8 * (r >> 2) + 4 * h;
                                list[qq * CAPB_ + slot] = make_float2(sc, __int_as_float(j));
                            }
                        }
                    }
                }
            }
        }
    };

    PASSLOOP(0, 0, 0);
    __syncthreads();                    // all histogram atomics done
    if (tid < 64) {
        int T = NB_ - 1, acc = 0;
        #pragma unroll 1
        for (int bin = 0; bin < NB_; ++bin) {
            acc += (int)hist[tid * NB_ + bin];
            if (acc >= KP_) { T = bin; break; }
        }
        edge[tid] = T;
        cnt[tid] = 0u;
    }
    __syncthreads();                    // edges ready, hist region reusable
    const int e0 = edge[ql] + 1, e1 = edge[32 + ql] + 1;   // +1 bin margin
    PASSLOOP(1, e0, e1);
    __syncthreads();                    // all appends done

    // exact rank-select top-28 by (score, idx); deterministic
    const int qq2 = tid >> 3, part = tid & 7;
    int cn = (int)cnt[qq2]; cn = cn > CAPB_ ? CAPB_ : cn;
    const size_t row = (size_t)b * N_ + qb + qq2;
    for (int e = part; e < cn; e += 8) {
        float2 me = list[qq2 * CAPB_ + e];
        float ms = me.x; int mj = __float_as_int(me.y);
        int rk = 0;
        for (int o = 0; o < cn; ++o) {
            float2 ot = list[qq2 * CAPB_ + o];
            rk += (ot.x < ms) || (ot.x == ms && __float_as_int(ot.y) < mj);
        }
        if (rk < KP_) idx24[row * KP_ + rk] = mj;
    }
}

// ---------------------------------------------------------------------------
// Kernel 3: f64 re-rank of the 28 candidates with the exact reference formula
// ---------------------------------------------------------------------------
__global__ __launch_bounds__(256) void k_rerank(const float* __restrict__ x,
                                                const double* __restrict__ sq64,
                                                const int* __restrict__ idx24,
                                                int* __restrict__ idx20) {
    __shared__ double dd[8 * KP_];
    __shared__ int    ii[8 * KP_];
    const int tid = threadIdx.x;
    const int rl = tid >> 5;       // row-in-block 0..7
    const int lane = tid & 31;
    const int row = blockIdx.x * 8 + rl;
    const int b = row >> 12, n = row & (N_ - 1);
    const int cand = (lane < KP_) ? (idx24[(size_t)row * KP_ + lane] & (N_ - 1)) : 0;
    const float* __restrict__ xb = x + (size_t)b * C_ * N_;
    double dot = 0.0;
    #pragma unroll 4
    for (int c = 0; c < C_; ++c) {
        double xn = (double)xb[(size_t)c * N_ + n];
        double xj = (double)xb[(size_t)c * N_ + cand];
        dot = fma(xn, xj, dot);
    }
    double d2 = (sq64[row] + sq64[b * N_ + cand]) - 2.0 * dot;
    if (lane < KP_) { dd[rl * KP_ + lane] = d2; ii[rl * KP_ + lane] = cand; }
    __syncthreads();
    if (lane < KP_) {
        int rank = 0;
        for (int t = 0; t < KP_; ++t) {
            double od = dd[rl * KP_ + t];
            int oi = ii[rl * KP_ + t];
            if (od < d2 || (od == d2 && oi < cand)) ++rank;
        }
        if (rank < KNN_) idx20[(size_t)row * KNN_ + rank] = cand;
    }
}

// ---------------------------------------------------------------------------
// Kernel 4: BN batch stats (sum, sumsq per channel), 32 rows/block
// ---------------------------------------------------------------------------
__global__ __launch_bounds__(256) void k_stats(const float* __restrict__ u,
                                               const float* __restrict__ v,
                                               const int* __restrict__ idx20,
                                               float* __restrict__ psum,
                                               float* __restrict__ psq) {
    __shared__ float red[512];
    const int tid = threadIdx.x;
    const int o = tid & 63, w = tid >> 6;
    const int base = blockIdx.x * 32;
    const int b = base >> 12;
    float s = 0.f, s2 = 0.f;
    for (int nn = w; nn < 32; nn += 4) {
        const int row = base + nn;
        const float uo = u[(size_t)row * 64 + o];      // bias pre-folded
        const int* ip = idx20 + (size_t)row * KNN_;
        #pragma unroll 4
        for (int k = 0; k < KNN_; ++k) {
            int j = ip[k];
            float y = uo + v[((size_t)b * N_ + j) * 64 + o];
            s += y;
            s2 = fmaf(y, y, s2);
        }
    }
    red[tid] = s;
    red[256 + tid] = s2;
    __syncthreads();
    if (tid < 64) {
        float t  = red[o] + red[64 + o] + red[128 + o] + red[192 + o];
        float t2 = red[256 + o] + red[320 + o] + red[384 + o] + red[448 + o];
        psum[blockIdx.x * 64 + o] = t;
        psq[blockIdx.x * 64 + o]  = t2;
    }
}

// Kernel 4b: finalize BN -> per-channel scale/shift (256 threads)
__global__ __launch_bounds__(256) void k_bn(const float* __restrict__ psum,
                                            const float* __restrict__ psq,
                                            const float* __restrict__ gamma,
                                            const float* __restrict__ beta,
                                            float* __restrict__ scsh) {
    __shared__ float red[512];
    const int tid = threadIdx.x;
    const int o = tid & 63, part = tid >> 6;
    float s = 0.f, s2 = 0.f;
    for (int i = part; i < 1024; i += 4) {
        s += psum[i * 64 + o];
        s2 += psq[i * 64 + o];
    }
    red[tid] = s;
    red[256 + tid] = s2;
    __syncthreads();
    if (tid < 64) {
        float t  = red[o] + red[64 + o] + red[128 + o] + red[192 + o];
        float t2 = red[256 + o] + red[320 + o] + red[384 + o] + red[448 + o];
        const float n = (float)B_ * (float)N_ * (float)KNN_;
        float mean = t / n;
        float var = t2 / n - mean * mean;
        float scale = gamma[o] / sqrtf(var + 1e-5f);
        scsh[o] = scale;
        scsh[64 + o] = beta[o] - mean * scale;
    }
}

// ---------------------------------------------------------------------------
// Kernel 5: out[b,o,n] = lrelu(scale*extreme_k(y) + shift), 64 rows/block
// ---------------------------------------------------------------------------
__global__ __launch_bounds__(256) void k_final(const float* __restrict__ u,
                                               const float* __restrict__ v,
                                               const int* __restrict__ idx20,
                                               const float* __restrict__ scsh,
                                               float* __restrict__ out) {
    __shared__ float tr[64 * 65];
    const int tid = threadIdx.x;
    const int o = tid & 63, w = tid >> 6;
    const int base = blockIdx.x * 64;
    const int b = base >> 12;
    const int nbase = base & (N_ - 1);
    const float sc = scsh[o];
    const float sh = scsh[64 + o];
    for (int nn = w; nn < 64; nn += 4) {
        const int row = base + nn;
        const float uo = u[(size_t)row * 64 + o];      // bias pre-folded
        const int* ip = idx20 + (size_t)row * KNN_;
        float mx = -INFINITY, mn = INFINITY;
        #pragma unroll 4
        for (int k = 0; k < KNN_; ++k) {
            int j = ip[k];
            float y = uo + v[((size_t)b * N_ + j) * 64 + o];
            mx = fmaxf(mx, y);
            mn = fminf(mn, y);
        }
        float best = (sc >= 0.f) ? mx : mn;
        float z = fmaf(best, sc, sh);
        tr[o * 65 + nn] = (z >= 0.f) ? z : 0.2f * z;
    }
    __syncthreads();
    for (int k = 0; k < 16; ++k) {      // 64*64 / 256
        int i = tid + k * 256;
        int o2 = i >> 6, n2 = i & 63;
        out[((size_t)b * 64 + o2) * N_ + nbase + n2] = tr[o2 * 65 + n2];
    }
}

// ---------------------------------------------------------------------------
extern "C" void kernel_launch(void* const* d_in, const int* in_sizes, int n_in,
                              void* d_out, int out_size, void* d_ws, size_t ws_size,
                              hipStream_t stream) {
    const float* x     = (const float*)d_in[0];
    const float* W     = (const float*)d_in[1];
    const float* bias  = (const float*)d_in[2];
    const float* gamma = (const float*)d_in[3];
    const float* beta  = (const float*)d_in[4];
    float* out = (float*)d_out;

    char* ws = (char*)d_ws;
    float*  u     = (float*)(ws + 0);           //  8,388,608
    float*  v     = (float*)(ws + 8388608);     //  8,388,608
    float*  sq32  = (float*)(ws + 16777216);    //    131,072
    double* sq64  = (double*)(ws + 16908288);   //    262,144
    float*  psum  = (float*)(ws + 17170432);    //    262,144 (1024x64)
    float*  psq   = (float*)(ws + 17432576);    //    262,144
    float*  scsh  = (float*)(ws + 17694720);    //        512
    int*    idx24 = (int*)(ws + 17695232);      //  3,670,016 (32768x28)
    uint4*  xh    = (uint4*)(ws + 21365248);    //  4,194,304
    int*    idx20 = (int*)(ws + 25559552);      //  2,621,440  (end ~26.9 MB)

    hipLaunchKernelGGL(k_prep,   dim3(512),  dim3(256), 0,     stream, x, W, bias, u, v, sq32, sq64, xh);
    hipLaunchKernelGGL(k_knn,    dim3(512),  dim3(512), 74240, stream, xh, sq32, idx24);
    hipLaunchKernelGGL(k_rerank, dim3(4096), dim3(256), 0,     stream, x, sq64, idx24, idx20);
    hipLaunchKernelGGL(k_stats,  dim3(1024), dim3(256), 0,     stream, u, v, idx20, psum, psq);
    hipLaunchKernelGGL(k_bn,     dim3(1),    dim3(256), 0,     stream, psum, psq, gamma, beta, scsh);
    hipLaunchKernelGGL(k_final,  dim3(512),  dim3(256), 0,     stream, u, v, idx20, scsh, out);
}

// Round 6
// 326.741 us; speedup vs baseline: 7.0981x; 1.3820x over previous
//
#include <hip/hip_runtime.h>
#include <math.h>

#define B_    8
#define C_    64
#define N_    4096
#define OUT_  64
#define KNN_  20
#define KP_   28     // candidates kept per row for f64 rerank (slack for hi-only bf16 Gram)

// histogram selection params (128 bins over [-80, 40), width 0.9375)
#define NB_   128
#define HLO_  (-80.0f)
#define HHI_  40.0f
#define HSC_  (128.0f/120.0f)
#define CAPB_ 80             // per-query collection capacity (>=7 sigma over ~33 expected)

typedef __attribute__((ext_vector_type(8)))  short bf16x8;
typedef __attribute__((ext_vector_type(16))) float f32x16;

__device__ __forceinline__ unsigned short bf16rtn(float f) {
    unsigned u = __float_as_uint(f);
    u += 0x7FFFu + ((u >> 16) & 1u);
    return (unsigned short)(u >> 16);
}

__device__ __forceinline__ void gld16(const void* g, void* l) {
    __builtin_amdgcn_global_load_lds((const __attribute__((address_space(1))) void*)g,
                                     (__attribute__((address_space(3))) void*)l, 16, 0, 0);
}

// ---------------------------------------------------------------------------
// Kernel 1: fused prep. Per block: 64-point tile of one batch.
//  - u = (W1-W2)·p + bias, v = W2·p      (bias pre-folded into u)
//  - xh = bf16(hi) pack, MFMA-frag-ready  [b][g][n] 16B units
//  - xT = transposed f32 copy [b*N+n][c]  (rerank gather-friendly; optional)
//  - sq32/sq64 = |p|^2
// ---------------------------------------------------------------------------
__global__ __launch_bounds__(256) void k_prep(const float* __restrict__ x,
                                              const float* __restrict__ W,
                                              const float* __restrict__ bias,
                                              float* __restrict__ u,
                                              float* __restrict__ v,
                                              float* __restrict__ sq32,
                                              double* __restrict__ sq64,
                                              uint4* __restrict__ xh,
                                              float* __restrict__ xT) {
    __shared__ float xs[64][65];     // [c][n]
    __shared__ float Wd[64 * 64];    // [c][o] = W1 - W2
    __shared__ float W2s[64 * 64];   // [c][o] = W2
    const int tid = threadIdx.x;
    const int b = blockIdx.x >> 6, nb = (blockIdx.x & 63) << 6;

    for (int k = 0; k < 16; ++k) {
        int i = tid + k * 256;
        int o = i & 63, c = i >> 6;
        float w1 = W[o * 128 + c];
        float w2 = W[o * 128 + 64 + c];
        Wd[c * 64 + o]  = w1 - w2;
        W2s[c * 64 + o] = w2;
    }
    for (int k = 0; k < 16; ++k) {
        int i = tid + k * 256;
        int c = i >> 6, n = i & 63;
        xs[c][n] = x[((size_t)b * 64 + c) * N_ + nb + n];
    }
    __syncthreads();

    const int o = tid & 63, w = tid >> 6;
    // --- u, v: 16 rows per thread, register accumulation ---
    float uacc[16], vacc[16];
    #pragma unroll
    for (int i = 0; i < 16; ++i) { uacc[i] = 0.f; vacc[i] = 0.f; }
    for (int c = 0; c < 64; ++c) {
        float wd = Wd[c * 64 + o], w2 = W2s[c * 64 + o];
        #pragma unroll
        for (int i = 0; i < 16; ++i) {
            float xc = xs[c][w * 16 + i];        // broadcast within wave
            uacc[i] = fmaf(wd, xc, uacc[i]);
            vacc[i] = fmaf(w2, xc, vacc[i]);
        }
    }
    const float bo = bias[o];
    #pragma unroll
    for (int i = 0; i < 16; ++i) {
        size_t row = (size_t)b * N_ + nb + w * 16 + i;
        u[row * 64 + o] = uacc[i] + bo;
        v[row * 64 + o] = vacc[i];
    }

    // --- pack xh (hi bf16 only): 2 channel-groups per thread ---
    {
        const int nl = tid & 63;
        #pragma unroll
        for (int gg = 0; gg < 2; ++gg) {
            const int g = (tid >> 6) + gg * 4;   // 0..7
            unsigned hw[4];
            #pragma unroll
            for (int e = 0; e < 4; ++e) {
                float x0 = xs[g * 8 + 2 * e][nl];
                float x1 = xs[g * 8 + 2 * e + 1][nl];
                hw[e] = (unsigned)bf16rtn(x0) | ((unsigned)bf16rtn(x1) << 16);
            }
            xh[(size_t)(b * 8 + g) * N_ + nb + nl] = make_uint4(hw[0], hw[1], hw[2], hw[3]);
        }
    }

    // --- transposed f32 copy (skipped when workspace too small) ---
    if (xT) {
        for (int k = 0; k < 16; ++k) {
            int i = tid + k * 256;
            int n = i >> 6, c = i & 63;
            xT[((size_t)b * N_ + nb + n) * 64 + c] = xs[c][n];
        }
    }

    // --- squared norms (f64 exact) ---
    if (tid < 64) {
        const int n = tid;
        double sq = 0.0;
        for (int c = 0; c < 64; ++c) {
            double xd = (double)xs[c][n];
            sq = fma(xd, xd, sq);
        }
        sq64[(size_t)b * N_ + nb + n] = sq;
        sq32[(size_t)b * N_ + nb + n] = (float)sq;
    }
}

// ---------------------------------------------------------------------------
// Kernel 2: MFMA Gram (bf16 hi x hi) + per-query top-28 via 2-pass histogram.
// ---------------------------------------------------------------------------
__global__ __launch_bounds__(512, 4) void k_knn(const uint4* __restrict__ xh,
                                                const float* __restrict__ sq32,
                                                int* __restrict__ idx24) {
    extern __shared__ char smem[];
    // 0     : staging, 8 waves x 4096 (Ah)
    // 32768 : union { hist u32[64*128] (32KB) ; list float2[64*80] (40KB) }
    // 73728 : cnt u32[64];  73984 : edge int[64];  total 74240
    unsigned* hist = (unsigned*)(smem + 32768);
    float2*   list = (float2*)(smem + 32768);
    unsigned* cnt  = (unsigned*)(smem + 73728);
    int*      edge = (int*)(smem + 73984);

    const int tid = threadIdx.x;
    const int b   = blockIdx.x >> 6;
    const int qb  = (blockIdx.x & 63) << 6;
    const int wid = tid >> 6, l = tid & 63, h = l >> 5, ql = l & 31;
    char* stg = smem + wid * 4096;
    const int jq = wid * 512;
    const uint4* xhb = xh + (size_t)b * 8 * N_;
    const float* sqb = sq32 + b * N_;

    for (int i = tid; i < 64 * NB_; i += 512) hist[i] = 0u;

    // B fragments (queries, hi only), persistent in regs
    bf16x8 Bh[2][4];
    #pragma unroll
    for (int s = 0; s < 2; ++s)
        #pragma unroll
        for (int kk = 0; kk < 4; ++kk)
            Bh[s][kk] = *(const bf16x8*)&xhb[(size_t)(2 * kk + h) * N_ + qb + s * 32 + ql];
    __syncthreads();   // hist zeroed

    auto STAGE = [&](int jb) {
        #pragma unroll
        for (int p = 0; p < 4; ++p)
            gld16(&xhb[(size_t)(2 * p + h) * N_ + jb + ql], stg + p * 1024);
    };

    auto PASSLOOP = [&](int pass, int e0, int e1) {
        STAGE(jq);
        #pragma unroll 1
        for (int t = 0; t < 16; ++t) {
            const int jb = jq + t * 32;
            asm volatile("s_waitcnt vmcnt(0)" ::: "memory");
            __builtin_amdgcn_sched_barrier(0);
            bf16x8 Ah[4];
            #pragma unroll
            for (int kk = 0; kk < 4; ++kk)
                Ah[kk] = *(const bf16x8*)(stg + kk * 1024 + l * 16);
            float4 q0 = *(const float4*)(sqb + jb + 4 * h);
            float4 q1 = *(const float4*)(sqb + jb + 8 + 4 * h);
            float4 q2 = *(const float4*)(sqb + jb + 16 + 4 * h);
            float4 q3 = *(const float4*)(sqb + jb + 24 + 4 * h);
            asm volatile("s_waitcnt lgkmcnt(0)" ::: "memory");
            __builtin_amdgcn_sched_barrier(0);
            if (t < 15) STAGE(jb + 32);

            f32x16 a0, a1;
            #pragma unroll
            for (int i = 0; i < 16; ++i) { a0[i] = 0.f; a1[i] = 0.f; }
            #pragma unroll
            for (int kk = 0; kk < 4; ++kk) {
                a0 = __builtin_amdgcn_mfma_f32_32x32x16_bf16(Ah[kk], Bh[0][kk], a0, 0, 0, 0);
                a1 = __builtin_amdgcn_mfma_f32_32x32x16_bf16(Ah[kk], Bh[1][kk], a1, 0, 0, 0);
            }
            float sq16[16];
            sq16[0]=q0.x; sq16[1]=q0.y; sq16[2]=q0.z; sq16[3]=q0.w;
            sq16[4]=q1.x; sq16[5]=q1.y; sq16[6]=q1.z; sq16[7]=q1.w;
            sq16[8]=q2.x; sq16[9]=q2.y; sq16[10]=q2.z; sq16[11]=q2.w;
            sq16[12]=q3.x; sq16[13]=q3.y; sq16[14]=q3.z; sq16[15]=q3.w;

            #pragma unroll
            for (int s = 0; s < 2; ++s) {
                const int qq = s * 32 + ql;
                const int eT = s ? e1 : e0;
                #pragma unroll
                for (int r = 0; r < 16; ++r) {
                    float av = s ? a1[r] : a0[r];
                    float sc = fmaf(-2.0f, av, sq16[r]);
                    if (sc < HHI_) {
                        int bin = (int)((sc - HLO_) * HSC_);
                        bin = bin < 0 ? 0 : bin;
                        if (pass == 0) {
                            atomicAdd(&hist[qq * NB_ + bin], 1u);
                        } else if (bin <= eT) {
                            unsigned slot = atomicAdd(&cnt[qq], 1u);
                            if (slot < CAPB_) {
                                int j = jb + (r & 3) + 8 * (r >> 2) + 4 * h;
                                list[qq * CAPB_ + slot] = make_float2(sc, __int_as_float(j));
                            }
                        }
                    }
                }
            }
        }
    };

    PASSLOOP(0, 0, 0);
    __syncthreads();
    if (tid < 64) {
        int T = NB_ - 1, acc = 0;
        #pragma unroll 1
        for (int bin = 0; bin < NB_; ++bin) {
            acc += (int)hist[tid * NB_ + bin];
            if (acc >= KP_) { T = bin; break; }
        }
        edge[tid] = T;
        cnt[tid] = 0u;
    }
    __syncthreads();
    const int e0 = edge[ql] + 1, e1 = edge[32 + ql] + 1;   // +1 bin margin
    PASSLOOP(1, e0, e1);
    __syncthreads();

    // exact rank-select top-28 by (score, idx); deterministic
    const int qq2 = tid >> 3, part = tid & 7;
    int cn = (int)cnt[qq2]; cn = cn > CAPB_ ? CAPB_ : cn;
    const size_t row = (size_t)b * N_ + qb + qq2;
    for (int e = part; e < cn; e += 8) {
        float2 me = list[qq2 * CAPB_ + e];
        float ms = me.x; int mj = __float_as_int(me.y);
        int rk = 0;
        for (int o = 0; o < cn; ++o) {
            float2 ot = list[qq2 * CAPB_ + o];
            rk += (ot.x < ms) || (ot.x == ms && __float_as_int(ot.y) < mj);
        }
        if (rk < KP_) idx24[row * KP_ + rk] = mj;
    }
}

// ---------------------------------------------------------------------------
// Kernel 3 (fast): f64 re-rank using transposed xT — candidate points are
// 256B-contiguous float4 streams; query staged in LDS; rank via __shfl.
// ---------------------------------------------------------------------------
__global__ __launch_bounds__(256) void k_rerank(const float* __restrict__ xT,
                                                const double* __restrict__ sq64,
                                                const int* __restrict__ idx24,
                                                int* __restrict__ idx20) {
    __shared__ float qs[8][64];
    const int tid = threadIdx.x;
    const int rl = tid >> 5, lane = tid & 31;
    const int rowBase = blockIdx.x * 8;
    #pragma unroll
    for (int i = 0; i < 2; ++i) {
        int idx = tid + i * 256;
        int r = idx >> 6, c = idx & 63;
        qs[r][c] = xT[(size_t)(rowBase + r) * 64 + c];
    }
    __syncthreads();
    const int row = rowBase + rl;
    const int b = row >> 12;
    const int cand = (lane < KP_) ? (idx24[(size_t)row * KP_ + lane] & (N_ - 1)) : 0;
    const float* __restrict__ cp = xT + ((size_t)b * N_ + cand) * 64;
    double dot = 0.0;
    #pragma unroll
    for (int c4 = 0; c4 < 16; ++c4) {
        float4 p4 = *(const float4*)(cp + c4 * 4);
        float4 q4 = *(const float4*)(&qs[rl][c4 * 4]);
        dot = fma((double)q4.x, (double)p4.x, dot);
        dot = fma((double)q4.y, (double)p4.y, dot);
        dot = fma((double)q4.z, (double)p4.z, dot);
        dot = fma((double)q4.w, (double)p4.w, dot);
    }
    double d2 = (sq64[row] + sq64[(size_t)b * N_ + cand]) - 2.0 * dot;
    int rank = 0;
    #pragma unroll 4
    for (int t = 0; t < KP_; ++t) {
        double od = __shfl(d2, t, 32);
        int    oi = __shfl(cand, t, 32);
        rank += (od < d2) || (od == d2 && oi < cand);
    }
    if (lane < KP_ && rank < KNN_) idx20[(size_t)row * KNN_ + rank] = cand;
}

// ---------------------------------------------------------------------------
// Kernel 3 (fallback): gather-from-x version (R5-proven), used if ws too small
// ---------------------------------------------------------------------------
__global__ __launch_bounds__(256) void k_rerank_fb(const float* __restrict__ x,
                                                   const double* __restrict__ sq64,
                                                   const int* __restrict__ idx24,
                                                   int* __restrict__ idx20) {
    __shared__ double dd[8 * KP_];
    __shared__ int    ii[8 * KP_];
    const int tid = threadIdx.x;
    const int rl = tid >> 5;
    const int lane = tid & 31;
    const int row = blockIdx.x * 8 + rl;
    const int b = row >> 12, n = row & (N_ - 1);
    const int cand = (lane < KP_) ? (idx24[(size_t)row * KP_ + lane] & (N_ - 1)) : 0;
    const float* __restrict__ xb = x + (size_t)b * C_ * N_;
    double dot = 0.0;
    #pragma unroll 4
    for (int c = 0; c < C_; ++c) {
        double xn = (double)xb[(size_t)c * N_ + n];
        double xj = (double)xb[(size_t)c * N_ + cand];
        dot = fma(xn, xj, dot);
    }
    double d2 = (sq64[row] + sq64[b * N_ + cand]) - 2.0 * dot;
    if (lane < KP_) { dd[rl * KP_ + lane] = d2; ii[rl * KP_ + lane] = cand; }
    __syncthreads();
    if (lane < KP_) {
        int rank = 0;
        for (int t = 0; t < KP_; ++t) {
            double od = dd[rl * KP_ + t];
            int oi = ii[rl * KP_ + t];
            if (od < d2 || (od == d2 && oi < cand)) ++rank;
        }
        if (rank < KNN_) idx20[(size_t)row * KNN_ + rank] = cand;
    }
}

// ---------------------------------------------------------------------------
// Kernel 4: BN batch stats (sum, sumsq per channel), 32 rows/block
// ---------------------------------------------------------------------------
__global__ __launch_bounds__(256) void k_stats(const float* __restrict__ u,
                                               const float* __restrict__ v,
                                               const int* __restrict__ idx20,
                                               float* __restrict__ psum,
                                               float* __restrict__ psq) {
    __shared__ float red[512];
    const int tid = threadIdx.x;
    const int o = tid & 63, w = tid >> 6;
    const int base = blockIdx.x * 32;
    const int b = base >> 12;
    float s = 0.f, s2 = 0.f;
    for (int nn = w; nn < 32; nn += 4) {
        const int row = base + nn;
        const float uo = u[(size_t)row * 64 + o];      // bias pre-folded
        const int* ip = idx20 + (size_t)row * KNN_;
        #pragma unroll 4
        for (int k = 0; k < KNN_; ++k) {
            int j = ip[k];
            float y = uo + v[((size_t)b * N_ + j) * 64 + o];
            s += y;
            s2 = fmaf(y, y, s2);
        }
    }
    red[tid] = s;
    red[256 + tid] = s2;
    __syncthreads();
    if (tid < 64) {
        float t  = red[o] + red[64 + o] + red[128 + o] + red[192 + o];
        float t2 = red[256 + o] + red[320 + o] + red[384 + o] + red[448 + o];
        psum[blockIdx.x * 64 + o] = t;
        psq[blockIdx.x * 64 + o]  = t2;
    }
}

// Kernel 4b: finalize BN -> per-channel scale/shift (256 threads)
__global__ __launch_bounds__(256) void k_bn(const float* __restrict__ psum,
                                            const float* __restrict__ psq,
                                            const float* __restrict__ gamma,
                                            const float* __restrict__ beta,
                                            float* __restrict__ scsh) {
    __shared__ float red[512];
    const int tid = threadIdx.x;
    const int o = tid & 63, part = tid >> 6;
    float s = 0.f, s2 = 0.f;
    for (int i = part; i < 1024; i += 4) {
        s += psum[i * 64 + o];
        s2 += psq[i * 64 + o];
    }
    red[tid] = s;
    red[256 + tid] = s2;
    __syncthreads();
    if (tid < 64) {
        float t  = red[o] + red[64 + o] + red[128 + o] + red[192 + o];
        float t2 = red[256 + o] + red[320 + o] + red[384 + o] + red[448 + o];
        const float n = (float)B_ * (float)N_ * (float)KNN_;
        float mean = t / n;
        float var = t2 / n - mean * mean;
        float scale = gamma[o] / sqrtf(var + 1e-5f);
        scsh[o] = scale;
        scsh[64 + o] = beta[o] - mean * scale;
    }
}

// ---------------------------------------------------------------------------
// Kernel 5: out[b,o,n] = lrelu(scale*extreme_k(y) + shift), 64 rows/block
// ---------------------------------------------------------------------------
__global__ __launch_bounds__(256) void k_final(const float* __restrict__ u,
                                               const float* __restrict__ v,
                                               const int* __restrict__ idx20,
                                               const float* __restrict__ scsh,
                                               float* __restrict__ out) {
    __shared__ float tr[64 * 65];
    const int tid = threadIdx.x;
    const int o = tid & 63, w = tid >> 6;
    const int base = blockIdx.x * 64;
    const int b = base >> 12;
    const int nbase = base & (N_ - 1);
    const float sc = scsh[o];
    const float sh = scsh[64 + o];
    for (int nn = w; nn < 64; nn += 4) {
        const int row = base + nn;
        const float uo = u[(size_t)row * 64 + o];      // bias pre-folded
        const int* ip = idx20 + (size_t)row * KNN_;
        float mx = -INFINITY, mn = INFINITY;
        #pragma unroll 4
        for (int k = 0; k < KNN_; ++k) {
            int j = ip[k];
            float y = uo + v[((size_t)b * N_ + j) * 64 + o];
            mx = fmaxf(mx, y);
            mn = fminf(mn, y);
        }
        float best = (sc >= 0.f) ? mx : mn;
        float z = fmaf(best, sc, sh);
        tr[o * 65 + nn] = (z >= 0.f) ? z : 0.2f * z;
    }
    __syncthreads();
    for (int k = 0; k < 16; ++k) {
        int i = tid + k * 256;
        int o2 = i >> 6, n2 = i & 63;
        out[((size_t)b * 64 + o2) * N_ + nbase + n2] = tr[o2 * 65 + n2];
    }
}

// ---------------------------------------------------------------------------
extern "C" void kernel_launch(void* const* d_in, const int* in_sizes, int n_in,
                              void* d_out, int out_size, void* d_ws, size_t ws_size,
                              hipStream_t stream) {
    const float* x     = (const float*)d_in[0];
    const float* W     = (const float*)d_in[1];
    const float* bias  = (const float*)d_in[2];
    const float* gamma = (const float*)d_in[3];
    const float* beta  = (const float*)d_in[4];
    float* out = (float*)d_out;

    char* ws = (char*)d_ws;
    // Layout A (with xT), need ~36.6 MB:
    //   u 8M | v 8M | xT 8M | xh 4M | idx24 3.67M | idx20 2.62M | small
    const size_t NEED_A = 36570112;
    const bool useA = (ws_size >= NEED_A);

    float *u, *v, *xT = nullptr, *sq32, *psum, *psq, *scsh;
    double* sq64;
    int *idx24, *idx20;
    uint4* xh;
    if (useA) {
        u     = (float*)(ws + 0);
        v     = (float*)(ws + 8388608);
        xT    = (float*)(ws + 16777216);
        xh    = (uint4*)(ws + 25165824);
        idx24 = (int*)(ws + 29360128);
        idx20 = (int*)(ws + 33030144);
        sq32  = (float*)(ws + 35651584);
        sq64  = (double*)(ws + 35782656);
        psum  = (float*)(ws + 36044800);
        psq   = (float*)(ws + 36306944);
        scsh  = (float*)(ws + 36569088);
    } else {
        u     = (float*)(ws + 0);
        v     = (float*)(ws + 8388608);
        sq32  = (float*)(ws + 16777216);
        sq64  = (double*)(ws + 16908288);
        psum  = (float*)(ws + 17170432);
        psq   = (float*)(ws + 17432576);
        scsh  = (float*)(ws + 17694720);
        idx24 = (int*)(ws + 17695232);
        xh    = (uint4*)(ws + 21365248);
        idx20 = (int*)(ws + 25559552);
    }

    hipLaunchKernelGGL(k_prep, dim3(512), dim3(256), 0, stream,
                       x, W, bias, u, v, sq32, sq64, xh, xT);
    hipLaunchKernelGGL(k_knn, dim3(512), dim3(512), 74240, stream, xh, sq32, idx24);
    if (useA) {
        hipLaunchKernelGGL(k_rerank, dim3(4096), dim3(256), 0, stream, xT, sq64, idx24, idx20);
    } else {
        hipLaunchKernelGGL(k_rerank_fb, dim3(4096), dim3(256), 0, stream, x, sq64, idx24, idx20);
    }
    hipLaunchKernelGGL(k_stats, dim3(1024), dim3(256), 0, stream, u, v, idx20, psum, psq);
    hipLaunchKernelGGL(k_bn,    dim3(1),    dim3(256), 0, stream, psum, psq, gamma, beta, scsh);
    hipLaunchKernelGGL(k_final, dim3(512),  dim3(256), 0, stream, u, v, idx20, scsh, out);
}